// Round 6
// baseline (116.203 us; speedup 1.0000x reference)
//
#include <hip/hip_runtime.h>

namespace {

constexpr int BATCH = 4, SEQ = 4096, DM = 256, DP = 80;
constexpr float ALPHA = 0.1f;

__device__ __forceinline__ float dot4(float4 a, float4 b) {
  return a.x * b.x + a.y * b.y + a.z * b.z + a.w * b.w;
}

__device__ __forceinline__ float wave_red(float s) {
  s += __shfl_down(s, 32); s += __shfl_down(s, 16); s += __shfl_down(s, 8);
  s += __shfl_down(s, 4);  s += __shfl_down(s, 2);  s += __shfl_down(s, 1);
  return s;
}

// 65-term dot: row = Mt + j*DP (16B aligned), v in LDS
__device__ __forceinline__ float rd65(const float* __restrict__ row,
                                      const float* v) {
  const float4* R = reinterpret_cast<const float4*>(row);
  const float4* V = reinterpret_cast<const float4*>(v);
  float a0 = 0.f, a1 = 0.f, a2 = 0.f, a3 = 0.f;
#pragma unroll
  for (int q = 0; q < 16; q += 4) {
    a0 += dot4(R[q + 0], V[q + 0]);
    a1 += dot4(R[q + 1], V[q + 1]);
    a2 += dot4(R[q + 2], V[q + 2]);
    a3 += dot4(R[q + 3], V[q + 3]);
  }
  return (a0 + a1) + (a2 + a3) + row[64] * v[64];
}

// dst[j<256] = sum_k v[k]*M[k][j]; 1024 lanes, 4 k-slices/output, shfl-reduced
__device__ __forceinline__ void nt256(const float* __restrict__ M,
                                      const float* v, float* dst, int t) {
  const int j = t >> 2, s = t & 3;
  const float* col = M + (size_t)(s * 64) * DM + j;
  const float* vv = v + s * 64;
  float a0 = 0.f, a1 = 0.f, a2 = 0.f, a3 = 0.f;
#pragma unroll
  for (int i = 0; i < 64; i += 4) {
    a0 += vv[i + 0] * col[(size_t)(i + 0) * DM];
    a1 += vv[i + 1] * col[(size_t)(i + 1) * DM];
    a2 += vv[i + 2] * col[(size_t)(i + 2) * DM];
    a3 += vv[i + 3] * col[(size_t)(i + 3) * DM];
  }
  float a = (a0 + a1) + (a2 + a3);
  a += __shfl_down(a, 2);
  a += __shfl_down(a, 1);
  if (s == 0) dst[j] = a;
}

// dst[j<256] = dot(M row j, v); u in [0,512), 2 slices/output
__device__ __forceinline__ void tn256_2(const float* __restrict__ M,
                                        const float* v, float* dst, int u) {
  const int j = u >> 1, s = u & 1;
  const float4* R = reinterpret_cast<const float4*>(M + (size_t)j * DM + s * 128);
  const float4* V = reinterpret_cast<const float4*>(v + s * 128);
  float a0 = 0.f, a1 = 0.f, a2 = 0.f, a3 = 0.f;
#pragma unroll
  for (int q = 0; q < 32; q += 4) {
    a0 += dot4(R[q + 0], V[q + 0]);
    a1 += dot4(R[q + 1], V[q + 1]);
    a2 += dot4(R[q + 2], V[q + 2]);
    a3 += dot4(R[q + 3], V[q + 3]);
  }
  float a = (a0 + a1) + (a2 + a3);
  a += __shfl_down(a, 1);
  if (s == 0) dst[j] = a;
}

// dst[i<80] = addv[i] + scale*dot(Mr row i, v); u in [0,320), 4 slices/output
__device__ __forceinline__ void er4(const float* __restrict__ Mr,
                                    const float* v, float* dst, int u,
                                    const float* addv, float scale) {
  const int i = u >> 2, s = u & 3;
  const float4* R = reinterpret_cast<const float4*>(Mr + (size_t)i * DM + s * 64);
  const float4* V = reinterpret_cast<const float4*>(v + s * 64);
  float a0 = 0.f, a1 = 0.f, a2 = 0.f, a3 = 0.f;
#pragma unroll
  for (int q = 0; q < 16; q += 4) {
    a0 += dot4(R[q + 0], V[q + 0]);
    a1 += dot4(R[q + 1], V[q + 1]);
    a2 += dot4(R[q + 2], V[q + 2]);
    a3 += dot4(R[q + 3], V[q + 3]);
  }
  float a = (a0 + a1) + (a2 + a3);
  a += __shfl_down(a, 2);
  a += __shfl_down(a, 1);
  if (s == 0) dst[i] = addv ? (addv[i] + scale * a) : a;
}

// ---------------------------------------------------------------------------
// Kernel 1: [0,nxtx) x^T x partials; [nxtx,nxtx+33) F0 rows; build; w1.
// ---------------------------------------------------------------------------
__global__ __launch_bounds__(256, 1)
void k_pre(const float* __restrict__ x, const float* __restrict__ Wemb,
           const float* __restrict__ bemb, const float* __restrict__ Wv,
           const float* __restrict__ Wout,
           float* __restrict__ Xp, float* __restrict__ cp,
           float* __restrict__ Et, float* __restrict__ F0t,
           float* __restrict__ Er, float* __restrict__ F0r,
           float* __restrict__ w1g, int nch) {
  const int bid = blockIdx.x, t = threadIdx.x;
  __shared__ __align__(16) float esT[512];
  __shared__ __align__(16) float4 ppA[4][64];
  __shared__ __align__(16) float4 ppB[4][64];
  __shared__ __align__(16) float xs[2][16][64];
  __shared__ __align__(16) float cs[16][64];

  const int nxtx = BATCH * nch * 2;

  if (bid < nxtx) {
    // ---- x^T x partials (double-buffered), col-halved ----
    const int per_b = nch * 2;
    const int b = bid / per_b, r5 = bid % per_b, ch = r5 >> 1, half = r5 & 1;
    const int chrows = SEQ / nch;
    const int nstage = chrows / 16;
    const float* xb = x + ((size_t)b * SEQ + (size_t)ch * chrows) * 64;
    const int trs = t >> 4, tcs = t & 15;
    const int tr2 = t >> 3, tc2 = t & 7;

    float acc[2][4] = {{0.f, 0.f, 0.f, 0.f}, {0.f, 0.f, 0.f, 0.f}};
    float4 csum = make_float4(0.f, 0.f, 0.f, 0.f);
    float4 v = *reinterpret_cast<const float4*>(xb + (size_t)trs * 64 + tcs * 4);
    int buf = 0;
    for (int st = 0; st < nstage; ++st) {
      *reinterpret_cast<float4*>(&xs[buf][trs][tcs * 4]) = v;
      csum.x += v.x; csum.y += v.y; csum.z += v.z; csum.w += v.w;
      __syncthreads();
      float4 vn = make_float4(0.f, 0.f, 0.f, 0.f);
      if (st + 1 < nstage)
        vn = *reinterpret_cast<const float4*>(
            xb + (size_t)((st + 1) * 16 + trs) * 64 + tcs * 4);
#pragma unroll
      for (int s = 0; s < 16; ++s) {
        const float a0 = xs[buf][s][tr2 * 2 + 0];
        const float a1 = xs[buf][s][tr2 * 2 + 1];
        const float4 b4 =
            *reinterpret_cast<const float4*>(&xs[buf][s][half * 32 + tc2 * 4]);
        acc[0][0] += a0 * b4.x; acc[0][1] += a0 * b4.y;
        acc[0][2] += a0 * b4.z; acc[0][3] += a0 * b4.w;
        acc[1][0] += a1 * b4.x; acc[1][1] += a1 * b4.y;
        acc[1][2] += a1 * b4.z; acc[1][3] += a1 * b4.w;
      }
      v = vn; buf ^= 1;
    }
    float* Xpb = Xp + (size_t)(b * nch + ch) * 4096;
#pragma unroll
    for (int rr = 0; rr < 2; ++rr) {
      const float4 s4 =
          make_float4(acc[rr][0], acc[rr][1], acc[rr][2], acc[rr][3]);
      *reinterpret_cast<float4*>(
          &Xpb[(size_t)(tr2 * 2 + rr) * 64 + half * 32 + tc2 * 4]) = s4;
    }
    if (half == 0) {
      *reinterpret_cast<float4*>(&cs[trs][tcs * 4]) = csum;
      __syncthreads();
      if (t < 64) {
        float s = 0.f;
#pragma unroll
        for (int g = 0; g < 16; ++g) s += cs[g][t];
        cp[(size_t)(b * nch + ch) * 64 + t] = s;
      }
    }
  } else if (bid < nxtx + 33) {
    // ---- F0bar rows r0,r0+1 : F0 = Ebar @ Wv0 (single NT pass) ----
    const int grp = bid - nxtx;
    const int r0 = grp * 2;
    const int nr = (r0 + 2 <= 65) ? 2 : 1;
    {
      const float v0 = (r0 < 64) ? Wemb[(size_t)r0 * DM + t] : bemb[t];
      float v1 = 0.f;
      if (nr == 2) v1 = (r0 + 1 < 64) ? Wemb[(size_t)(r0 + 1) * DM + t] : bemb[t];
      esT[t * 2] = v0; esT[t * 2 + 1] = v1;
    }
    __syncthreads();
    const int jg = t & 63, ks = t >> 6, j0 = jg * 4;
    float4 A0 = make_float4(0.f, 0.f, 0.f, 0.f);
    float4 A1 = make_float4(0.f, 0.f, 0.f, 0.f);
    const int kbeg = ks * 64;
#pragma unroll 8
    for (int i = 0; i < 64; ++i) {
      const int k = kbeg + i;
      const float4 m = *reinterpret_cast<const float4*>(Wv + (size_t)k * DM + j0);
      const float s0 = esT[k * 2], s1 = esT[k * 2 + 1];
      A0.x += s0 * m.x; A0.y += s0 * m.y; A0.z += s0 * m.z; A0.w += s0 * m.w;
      A1.x += s1 * m.x; A1.y += s1 * m.y; A1.z += s1 * m.z; A1.w += s1 * m.w;
    }
    ppA[ks][jg] = A0; ppB[ks][jg] = A1;
    __syncthreads();
    if (t < 128) {
      const int rr = t >> 6, jj = t & 63;
      float4 s;
      if (rr == 0) {
        const float4 q0 = ppA[0][jj], q1 = ppA[1][jj];
        const float4 q2 = ppA[2][jj], q3 = ppA[3][jj];
        s = make_float4((q0.x + q1.x) + (q2.x + q3.x),
                        (q0.y + q1.y) + (q2.y + q3.y),
                        (q0.z + q1.z) + (q2.z + q3.z),
                        (q0.w + q1.w) + (q2.w + q3.w));
      } else {
        const float4 q0 = ppB[0][jj], q1 = ppB[1][jj];
        const float4 q2 = ppB[2][jj], q3 = ppB[3][jj];
        s = make_float4((q0.x + q1.x) + (q2.x + q3.x),
                        (q0.y + q1.y) + (q2.y + q3.y),
                        (q0.z + q1.z) + (q2.z + q3.z),
                        (q0.w + q1.w) + (q2.w + q3.w));
      }
      if (rr < nr) {
        *reinterpret_cast<float4*>(&F0r[(size_t)(r0 + rr) * DM + jj * 4]) = s;
        F0t[(size_t)(jj * 4 + 0) * DP + r0 + rr] = s.x;
        F0t[(size_t)(jj * 4 + 1) * DP + r0 + rr] = s.y;
        F0t[(size_t)(jj * 4 + 2) * DP + r0 + rr] = s.z;
        F0t[(size_t)(jj * 4 + 3) * DP + r0 + rr] = s.w;
      }
    }
  } else if (bid == nxtx + 33) {
    // ---- Et / Er build + all pad zeroing ----
    for (int i = 0; i < 64; ++i) {
      const float w = Wemb[(size_t)i * DM + t];
      Et[(size_t)t * DP + i] = w;
      Er[(size_t)i * DM + t] = w;
    }
    Et[(size_t)t * DP + 64] = bemb[t];
    Er[(size_t)64 * DM + t] = bemb[t];
    for (int i = 65; i < DP; ++i) {
      Et[(size_t)t * DP + i] = 0.f;
      F0t[(size_t)t * DP + i] = 0.f;
    }
    for (int i = 0; i < 15; ++i) {
      Er[(size_t)(65 + i) * DM + t] = 0.f;
      F0r[(size_t)(65 + i) * DM + t] = 0.f;
    }
  } else {
    // ---- w1 = Wv1 @ Wout ----
    esT[t] = Wout[t];
    __syncthreads();
    const float* Wv1 = Wv + (size_t)DM * DM;
    const float4* R = reinterpret_cast<const float4*>(Wv1 + (size_t)t * DM);
    const float4* V = reinterpret_cast<const float4*>(esT);
    float a0 = 0.f, a1 = 0.f, a2 = 0.f, a3 = 0.f;
#pragma unroll 4
    for (int q = 0; q < 64; q += 4) {
      a0 += dot4(R[q + 0], V[q + 0]); a1 += dot4(R[q + 1], V[q + 1]);
      a2 += dot4(R[q + 2], V[q + 2]); a3 += dot4(R[q + 3], V[q + 3]);
    }
    w1g[t] = (a0 + a1) + (a2 + a3);
  }
}

// ---------------------------------------------------------------------------
// Kernel 2 (4 blocks x 1024): per-batch chain; Q_l applied as NT+TN on raw
// Wq/Wk. out = cbar.eo + a*(g.f0) + a*(pv.Xq) + bout
// ---------------------------------------------------------------------------
__global__ __launch_bounds__(1024, 4)
void k_post(const float* __restrict__ Xp, const float* __restrict__ cp,
            const float* __restrict__ Et, const float* __restrict__ F0t,
            const float* __restrict__ Er, const float* __restrict__ F0r,
            const float* __restrict__ Wq, const float* __restrict__ Wk,
            const float* __restrict__ Wout, const float* __restrict__ bout,
            const float* __restrict__ w1g, float* __restrict__ out, int nch) {
  const int b = blockIdx.x, t = threadIdx.x;
  __shared__ __align__(16) float X[DP][84];
  __shared__ __align__(16) float wol[256], w1l[256];
  __shared__ __align__(16) float cl[DP], eo[DP], e1[DP], f0[DP], f1[DP];
  __shared__ __align__(16) float u2[256], ua[256], al[256];
  __shared__ __align__(16) float y8[DP], z2[256], cM0[DP], g8[DP];
  __shared__ __align__(16) float za[256], zb[256], qv[DP];
  __shared__ __align__(16) float hs[256], hsa[256], hv[256];
  __shared__ __align__(16) float Xq[DP], rE[DP], rF[DP];
  __shared__ __align__(16) float t1v[DP], t2v[256], va[256], vb[256];
  __shared__ __align__(16) float pv[DP], pr0[DP], pr1[DP];
  __shared__ float dots[3];

  const float* Wq0 = Wq;  const float* Wq1 = Wq + (size_t)DM * DM;
  const float* Wk0 = Wk;  const float* Wk1 = Wk + (size_t)DM * DM;

  // ---- B0: X core reduce + X pads + stage wol/w1l
  {
    const int e = t * 4;
    float4 a = make_float4(0.f, 0.f, 0.f, 0.f);
#pragma unroll 4
    for (int ch = 0; ch < nch; ++ch) {
      const float4 p = *reinterpret_cast<const float4*>(
          Xp + (size_t)(b * nch + ch) * 4096 + e);
      a.x += p.x; a.y += p.y; a.z += p.z; a.w += p.w;
    }
    const int r = e >> 6, c = e & 63;
    X[r][c] = a.x; X[r][c + 1] = a.y; X[r][c + 2] = a.z; X[r][c + 3] = a.w;
    for (int n = t; n < 2495; n += 1024) {
      if (n < 1235) X[n / 19][65 + n % 19] = 0.f;
      else { const int m = n - 1235; X[65 + m / 84][m % 84] = 0.f; }
    }
    if (t < 256) wol[t] = Wout[t];
    else if (t < 512) w1l[t - 256] = w1g[t - 256];
  }
  __syncthreads();

  // ---- B1: cl (+pads) || eo || e1 || f0
  if (t < 64) {
    float s = 0.f;
#pragma unroll 4
    for (int ch = 0; ch < nch; ++ch) s += cp[(size_t)(b * nch + ch) * 64 + t];
    cl[t] = s;
    if (t == 0) cl[64] = (float)SEQ;
    if (t == 1) for (int p = 65; p < DP; ++p) cl[p] = 0.f;
  } else if (t < 384) er4(Er, wol, eo, t - 64, nullptr, 0.f);
  else if (t < 704) er4(Er, w1l, e1, t - 384, nullptr, 0.f);
  else er4(F0r, wol, f0, t - 704, nullptr, 0.f);
  __syncthreads();

  // ---- B2: u = cbar@Ebar || f1 = F0bar@w1 || X borders
  if (t < 256) u2[t] = rd65(Et + (size_t)t * DP, cl);
  else if (t < 576) er4(F0r, w1l, f1, t - 256, nullptr, 0.f);
  else if (t < 705) {
    const int n = t - 576;
    if (n < 64) X[n][64] = cl[n];
    else if (n == 64) X[64][64] = (float)SEQ;
    else X[64][n - 65] = cl[n - 65];
  }
  __syncthreads();

  // ---- B3: ua = u @ Wq0
  nt256(Wq0, u2, ua, t);
  __syncthreads();

  // ---- B4: al = ua @ Wk0^T || y = Xbar f1
  if (t < 512) tn256_2(Wk0, ua, al, t);
  else if (t < 592) {
    const int i = t - 512; float s = 0.f;
    for (int j = 0; j < DP; ++j) s += X[i][j] * f1[j];
    y8[i] = s;
  }
  __syncthreads();

  // ---- B5: cM0 = al @ Ebar^T || z2 = y @ Ebar
  if (t < 320) er4(Er, al, cM0, t, nullptr, 0.f);
  else if (t < 576) z2[t - 320] = rd65(Et + (size_t)(t - 320) * DP, y8);
  __syncthreads();

  // ---- B6: za = z2 @ Wk0
  nt256(Wk0, z2, za, t);
  __syncthreads();

  // ---- B7: zb = za @ Wq0^T || g = cM0 Xbar
  if (t < 512) tn256_2(Wq0, za, zb, t);
  else if (t < 592) {
    const int j = t - 512; float s = 0.f;
    for (int i = 0; i < DP; ++i) s += cM0[i] * X[i][j];
    g8[j] = s;
  }
  __syncthreads();

  // ---- B8: hs = u + a*(g @ F0bar) || qv = e1 + a*(zb @ Ebar^T)
  if (t < 256) hs[t] = u2[t] + ALPHA * rd65(F0t + (size_t)t * DP, g8);
  else if (t >= 320 && t < 640) er4(Er, zb, qv, t - 320, e1, ALPHA);
  __syncthreads();

  // ---- B9: hsa = hs @ Wq1
  nt256(Wq1, hs, hsa, t);
  __syncthreads();

  // ---- B10: hv = hsa @ Wk1^T || Xq = Xbar qv
  if (t < 512) tn256_2(Wk1, hsa, hv, t);
  else if (t < 592) {
    const int i = t - 512; float s = 0.f;
    for (int j = 0; j < DP; ++j) s += X[i][j] * qv[j];
    Xq[i] = s;
  }
  __syncthreads();

  // ---- B11: rE = hv @ Ebar^T || rF = hv @ F0bar^T
  if (t < 320) er4(Er, hv, rE, t, nullptr, 0.f);
  else if (t < 640) er4(F0r, hv, rF, t - 320, nullptr, 0.f);
  __syncthreads();

  // ---- B12: t1 = rF Xbar
  if (t < 80) {
    float s = 0.f;
    for (int i = 0; i < DP; ++i) s += rF[i] * X[i][t];
    t1v[t] = s;
  }
  __syncthreads();

  // ---- B13: t2 = t1 @ Ebar
  if (t < 256) t2v[t] = rd65(Et + (size_t)t * DP, t1v);
  __syncthreads();

  // ---- B14: va = t2 @ Wk0
  nt256(Wk0, t2v, va, t);
  __syncthreads();

  // ---- B15: vb = va @ Wq0^T || pr0, pr1
  if (t < 512) tn256_2(Wq0, va, vb, t);
  else if (t < 592) { const int i = t - 512; pr0[i] = cl[i] * eo[i]; }
  else if (t < 672) { const int i = t - 592; pr1[i] = g8[i] * f0[i]; }
  __syncthreads();

  // ---- B16: pv = rE + a*(vb @ Ebar^T)
  if (t < 320) er4(Er, vb, pv, t, rE, ALPHA);
  __syncthreads();

  // ---- B17: three 80-dots
  const int w = t >> 6, l = t & 63;
  if (w < 3) {
    float v;
    if (w == 0)      v = pr0[l] + ((l < 16) ? pr0[64 + l] : 0.f);
    else if (w == 1) v = pr1[l] + ((l < 16) ? pr1[64 + l] : 0.f);
    else v = pv[l] * Xq[l] + ((l < 16) ? pv[64 + l] * Xq[64 + l] : 0.f);
    v = wave_red(v);
    if (l == 0) dots[w] = v;
  }
  __syncthreads();
  if (t == 0) out[b] = dots[0] + ALPHA * dots[1] + ALPHA * dots[2] + bout[0];
}

}  // namespace

extern "C" void kernel_launch(void* const* d_in, const int* in_sizes, int n_in,
                              void* d_out, int out_size, void* d_ws, size_t ws_size,
                              hipStream_t stream) {
  const float* x    = (const float*)d_in[0];
  const float* Wemb = (const float*)d_in[1];
  const float* bemb = (const float*)d_in[2];
  const float* Wq   = (const float*)d_in[3];
  const float* Wk   = (const float*)d_in[4];
  const float* Wv   = (const float*)d_in[5];
  const float* Wout = (const float*)d_in[6];
  const float* bout = (const float*)d_in[7];
  float* out = (float*)d_out;

  const size_t fixed = (size_t)2 * 256 * DP + (size_t)2 * DP * 256 + 256;
  int nch = 16;
  while (nch > 4 &&
         ((size_t)BATCH * nch * (4096 + 64) + fixed) * sizeof(float) > ws_size)
    nch >>= 1;

  float* p = (float*)d_ws;
  float* Xp  = p; p += (size_t)BATCH * nch * 4096;
  float* cp  = p; p += (size_t)BATCH * nch * 64;
  float* Et  = p; p += 256 * DP;
  float* F0t = p; p += 256 * DP;
  float* Er  = p; p += DP * 256;
  float* F0r = p; p += DP * 256;
  float* w1g = p; p += 256;

  const int nblk = BATCH * nch * 2 + 33 + 2;
  k_pre<<<nblk, 256, 0, stream>>>(x, Wemb, bemb, Wv, Wout,
                                  Xp, cp, Et, F0t, Er, F0r, w1g, nch);
  k_post<<<BATCH, 1024, 0, stream>>>(Xp, cp, Et, F0t, Er, F0r, Wq, Wk,
                                     Wout, bout, w1g, out, nch);
}

// Round 7
// 52.472 us; speedup vs baseline: 2.2146x; 2.2146x over previous
//
#include <hip/hip_runtime.h>

namespace {

constexpr int BATCH = 4, SEQ = 4096, DM = 256, DP = 80, NCH = 16;
constexpr float ALPHA = 0.1f;

__device__ __forceinline__ float dot4(float4 a, float4 b) {
  return a.x * b.x + a.y * b.y + a.z * b.z + a.w * b.w;
}

__device__ __forceinline__ float dot4f4(const float4* __restrict__ R,
                                        const float4* V) {
  return (dot4(R[0], V[0]) + dot4(R[1], V[1])) +
         (dot4(R[2], V[2]) + dot4(R[3], V[3]));
}
__device__ __forceinline__ float dot8f4(const float4* __restrict__ R,
                                        const float4* V) {
  float a0 = 0.f, a1 = 0.f, a2 = 0.f, a3 = 0.f;
#pragma unroll
  for (int q = 0; q < 8; q += 4) {
    a0 += dot4(R[q + 0], V[q + 0]); a1 += dot4(R[q + 1], V[q + 1]);
    a2 += dot4(R[q + 2], V[q + 2]); a3 += dot4(R[q + 3], V[q + 3]);
  }
  return (a0 + a1) + (a2 + a3);
}
__device__ __forceinline__ float dot16f4(const float4* __restrict__ R,
                                         const float4* V) {
  float a0 = 0.f, a1 = 0.f, a2 = 0.f, a3 = 0.f;
#pragma unroll
  for (int q = 0; q < 16; q += 4) {
    a0 += dot4(R[q + 0], V[q + 0]); a1 += dot4(R[q + 1], V[q + 1]);
    a2 += dot4(R[q + 2], V[q + 2]); a3 += dot4(R[q + 3], V[q + 3]);
  }
  return (a0 + a1) + (a2 + a3);
}
__device__ __forceinline__ float dot64f4(const float4* __restrict__ R,
                                         const float4* V) {
  float a0 = 0.f, a1 = 0.f, a2 = 0.f, a3 = 0.f;
#pragma unroll 16
  for (int q = 0; q < 64; q += 4) {
    a0 += dot4(R[q + 0], V[q + 0]); a1 += dot4(R[q + 1], V[q + 1]);
    a2 += dot4(R[q + 2], V[q + 2]); a3 += dot4(R[q + 3], V[q + 3]);
  }
  return (a0 + a1) + (a2 + a3);
}

__device__ __forceinline__ float wave_red(float s) {
  s += __shfl_down(s, 32); s += __shfl_down(s, 16); s += __shfl_down(s, 8);
  s += __shfl_down(s, 4);  s += __shfl_down(s, 2);  s += __shfl_down(s, 1);
  return s;
}

// 65-term row dot, 2-way sliced (s in {0,1}); row stride-80 f4-aligned
__device__ __forceinline__ float rd65h(const float* __restrict__ row,
                                       const float* v, int s) {
  float a = dot8f4(reinterpret_cast<const float4*>(row + s * 32),
                   reinterpret_cast<const float4*>(v + s * 32));
  if (s) a += row[64] * v[64];
  return a;
}
// 65-term row dot, 4-way sliced (s in {0..3})
__device__ __forceinline__ float rd65q(const float* __restrict__ row,
                                       const float* v, int s) {
  float a = dot4f4(reinterpret_cast<const float4*>(row + s * 16),
                   reinterpret_cast<const float4*>(v + s * 16));
  if (s == 3) a += row[64] * v[64];
  return a;
}
// 256-term row dot, 4-way sliced; dst[i] = addv[i] + scale*dot (or plain)
__device__ __forceinline__ void er4(const float* __restrict__ Mr,
                                    const float* v, float* dst, int u,
                                    const float* addv, float scale) {
  const int i = u >> 2, s = u & 3;
  float a = dot16f4(reinterpret_cast<const float4*>(Mr + (size_t)i * DM + s * 64),
                    reinterpret_cast<const float4*>(v + s * 64));
  a += __shfl_down(a, 2); a += __shfl_down(a, 1);
  if (s == 0) dst[i] = addv ? (addv[i] + scale * a) : a;
}
// 256-term row dot, 8-way sliced
__device__ __forceinline__ void er8(const float* __restrict__ Mr,
                                    const float* v, float* dst, int u) {
  const int i = u >> 3, s = u & 7;
  float a = dot8f4(reinterpret_cast<const float4*>(Mr + (size_t)i * DM + s * 32),
                   reinterpret_cast<const float4*>(v + s * 32));
  a += __shfl_down(a, 4); a += __shfl_down(a, 2); a += __shfl_down(a, 1);
  if (s == 0) dst[i] = a;
}

// ---------------------------------------------------------------------------
// K1 roles by bid: [0,33) Y1(+F0), [33,66) Z0, [66,99) Z1, [99,227) x^T x,
// 227 build Et/Er+pads, 228 w1, 229 eo, 230 f0.
// ---------------------------------------------------------------------------
__global__ __launch_bounds__(256, 2)
void k_pre(const float* __restrict__ x, const float* __restrict__ Wemb,
           const float* __restrict__ bemb, const float* __restrict__ Wq,
           const float* __restrict__ Wk, const float* __restrict__ Wv,
           const float* __restrict__ Wout,
           float* __restrict__ Xp, float* __restrict__ cp,
           float* __restrict__ Z0t, float* __restrict__ Z1t,
           float* __restrict__ Y1t, float* __restrict__ F0t,
           float* __restrict__ Et, float* __restrict__ Er,
           float* __restrict__ F0r, float* __restrict__ Z0r,
           float* __restrict__ w1g, float* __restrict__ eog,
           float* __restrict__ f0g) {
  const int bid = blockIdx.x, t = threadIdx.x;
  __shared__ __align__(16) float esT[512];
  __shared__ __align__(16) float fsT[512];
  __shared__ __align__(16) float psT[512];
  __shared__ __align__(16) float4 ppA[4][64];
  __shared__ __align__(16) float4 ppB[4][64];
  __shared__ __align__(16) float xs[2][16][64];
  __shared__ __align__(16) float cs[16][64];
  __shared__ __align__(16) float vbuf[256];
  __shared__ __align__(16) float a0s[256];

  if (bid < 99) {
    // ---------------- chain-row blocks ----------------
    const int role = bid / 33, grp = bid % 33;   // 0:Y1 1:Z0 2:Z1
    const int r0 = grp * 2, nr = (r0 == 64) ? 1 : 2;
    {
      const float v0 = (r0 < 64) ? Wemb[(size_t)r0 * DM + t] : bemb[t];
      float v1 = 0.f;
      if (nr == 2) v1 = (r0 + 1 < 64) ? Wemb[(size_t)(r0 + 1) * DM + t] : bemb[t];
      esT[t * 2] = v0; esT[t * 2 + 1] = v1;
    }
    __syncthreads();
    const int jg = t & 63, ks = t >> 6, j0 = jg * 4;

    auto nt_pass = [&](const float* src, const float* __restrict__ M,
                       float* dstT, bool f0st) {
      float4 A0 = make_float4(0.f, 0.f, 0.f, 0.f);
      float4 A1 = make_float4(0.f, 0.f, 0.f, 0.f);
      const float* Mp = M + (size_t)(ks * 64) * DM + j0;
#pragma unroll 16
      for (int i = 0; i < 64; ++i) {
        const float4 m = *reinterpret_cast<const float4*>(Mp + (size_t)i * DM);
        const float s0 = src[(ks * 64 + i) * 2];
        const float s1 = src[(ks * 64 + i) * 2 + 1];
        A0.x += s0 * m.x; A0.y += s0 * m.y; A0.z += s0 * m.z; A0.w += s0 * m.w;
        A1.x += s1 * m.x; A1.y += s1 * m.y; A1.z += s1 * m.z; A1.w += s1 * m.w;
      }
      ppA[ks][jg] = A0; ppB[ks][jg] = A1;
      __syncthreads();
      if (t < 128) {
        const int rr = t >> 6, jj = t & 63;
        float4 q0, q1, q2, q3;
        if (rr == 0) { q0 = ppA[0][jj]; q1 = ppA[1][jj]; q2 = ppA[2][jj]; q3 = ppA[3][jj]; }
        else         { q0 = ppB[0][jj]; q1 = ppB[1][jj]; q2 = ppB[2][jj]; q3 = ppB[3][jj]; }
        const float4 s = make_float4((q0.x + q1.x) + (q2.x + q3.x),
                                     (q0.y + q1.y) + (q2.y + q3.y),
                                     (q0.z + q1.z) + (q2.z + q3.z),
                                     (q0.w + q1.w) + (q2.w + q3.w));
        dstT[(jj * 4 + 0) * 2 + rr] = s.x;
        dstT[(jj * 4 + 1) * 2 + rr] = s.y;
        dstT[(jj * 4 + 2) * 2 + rr] = s.z;
        dstT[(jj * 4 + 3) * 2 + rr] = s.w;
        if (f0st && rr < nr) {
          *reinterpret_cast<float4*>(&F0r[(size_t)(r0 + rr) * DM + jj * 4]) = s;
          F0t[(size_t)(jj * 4 + 0) * DP + r0 + rr] = s.x;
          F0t[(size_t)(jj * 4 + 1) * DP + r0 + rr] = s.y;
          F0t[(size_t)(jj * 4 + 2) * DP + r0 + rr] = s.z;
          F0t[(size_t)(jj * 4 + 3) * DP + r0 + rr] = s.w;
        }
      }
      __syncthreads();
    };

    const float* src2 = esT;
    const float* M1; const float* M2; float* dstG; bool isZ0 = false;
    if (role == 0) {
      nt_pass(esT, Wv, fsT, true);            // F0 = Ebar @ Wv0 (side-store)
      src2 = fsT;
      M1 = Wq + (size_t)DM * DM; M2 = Wk + (size_t)DM * DM; dstG = Y1t;
    } else if (role == 1) {
      M1 = Wq; M2 = Wk; dstG = Z0t; isZ0 = true;
    } else {
      M1 = Wq + (size_t)DM * DM; M2 = Wk + (size_t)DM * DM; dstG = Z1t;
    }
    nt_pass(src2, M1, psT, false);

    {  // TN: dst[j][r] = sum_k p[k][r] * M2[j][k]
      const int j = t;
      const float4* Mrow = reinterpret_cast<const float4*>(M2 + (size_t)j * DM);
      float ac0 = 0.f, ac1 = 0.f;
#pragma unroll 16
      for (int u = 0; u < 64; ++u) {
        const float4 m = Mrow[u];
        const int k4 = u * 4;
        ac0 += (m.x * psT[(k4 + 0) * 2] + m.y * psT[(k4 + 1) * 2]) +
               (m.z * psT[(k4 + 2) * 2] + m.w * psT[(k4 + 3) * 2]);
        ac1 += (m.x * psT[(k4 + 0) * 2 + 1] + m.y * psT[(k4 + 1) * 2 + 1]) +
               (m.z * psT[(k4 + 2) * 2 + 1] + m.w * psT[(k4 + 3) * 2 + 1]);
      }
      dstG[(size_t)j * DP + r0] = ac0;
      if (isZ0) Z0r[(size_t)r0 * DM + j] = ac0;
      if (nr == 2) {
        dstG[(size_t)j * DP + r0 + 1] = ac1;
        if (isZ0) Z0r[(size_t)(r0 + 1) * DM + j] = ac1;
      }
    }
  } else if (bid < 99 + BATCH * NCH * 2) {
    // ---------------- x^T x partials (double-buffered, col-halved) --------
    const int idx = bid - 99;
    const int per_b = NCH * 2;
    const int b = idx / per_b, r5 = idx % per_b, ch = r5 >> 1, half = r5 & 1;
    const int chrows = SEQ / NCH, nstage = chrows / 16;
    const float* xb = x + ((size_t)b * SEQ + (size_t)ch * chrows) * 64;
    const int trs = t >> 4, tcs = t & 15;
    const int tr2 = t >> 3, tc2 = t & 7;

    float acc[2][4] = {{0.f, 0.f, 0.f, 0.f}, {0.f, 0.f, 0.f, 0.f}};
    float4 csum = make_float4(0.f, 0.f, 0.f, 0.f);
    float4 v = *reinterpret_cast<const float4*>(xb + (size_t)trs * 64 + tcs * 4);
    int buf = 0;
    for (int st = 0; st < nstage; ++st) {
      *reinterpret_cast<float4*>(&xs[buf][trs][tcs * 4]) = v;
      csum.x += v.x; csum.y += v.y; csum.z += v.z; csum.w += v.w;
      __syncthreads();
      float4 vn = make_float4(0.f, 0.f, 0.f, 0.f);
      if (st + 1 < nstage)
        vn = *reinterpret_cast<const float4*>(
            xb + (size_t)((st + 1) * 16 + trs) * 64 + tcs * 4);
#pragma unroll
      for (int s = 0; s < 16; ++s) {
        const float a0 = xs[buf][s][tr2 * 2 + 0];
        const float a1 = xs[buf][s][tr2 * 2 + 1];
        const float4 b4 =
            *reinterpret_cast<const float4*>(&xs[buf][s][half * 32 + tc2 * 4]);
        acc[0][0] += a0 * b4.x; acc[0][1] += a0 * b4.y;
        acc[0][2] += a0 * b4.z; acc[0][3] += a0 * b4.w;
        acc[1][0] += a1 * b4.x; acc[1][1] += a1 * b4.y;
        acc[1][2] += a1 * b4.z; acc[1][3] += a1 * b4.w;
      }
      v = vn; buf ^= 1;
    }
    float* Xpb = Xp + (size_t)(b * NCH + ch) * 4096;
#pragma unroll
    for (int rr = 0; rr < 2; ++rr) {
      const float4 s4 = make_float4(acc[rr][0], acc[rr][1], acc[rr][2], acc[rr][3]);
      *reinterpret_cast<float4*>(
          &Xpb[(size_t)(tr2 * 2 + rr) * 64 + half * 32 + tc2 * 4]) = s4;
    }
    if (half == 0) {
      *reinterpret_cast<float4*>(&cs[trs][tcs * 4]) = csum;
      __syncthreads();
      if (t < 64) {
        float s = 0.f;
#pragma unroll
        for (int g = 0; g < 16; ++g) s += cs[g][t];
        cp[(size_t)(b * NCH + ch) * 64 + t] = s;
      }
    }
  } else if (bid == 227) {
    // ---------------- Et/Er build + pad-row zeroing ----------------
    for (int i = 0; i < 64; ++i) {
      const float w = Wemb[(size_t)i * DM + t];
      Et[(size_t)t * DP + i] = w;
      Er[(size_t)i * DM + t] = w;
    }
    Et[(size_t)t * DP + 64] = bemb[t];
    Er[(size_t)64 * DM + t] = bemb[t];
    for (int i = 65; i < DP; ++i) {
      Er[(size_t)i * DM + t] = 0.f;
      F0r[(size_t)i * DM + t] = 0.f;
      Z0r[(size_t)i * DM + t] = 0.f;
    }
  } else if (bid == 228) {
    // ---------------- w1 = Wv1 @ Wout ----------------
    vbuf[t] = Wout[t];
    __syncthreads();
    const float* Wv1 = Wv + (size_t)DM * DM;
    w1g[t] = dot64f4(reinterpret_cast<const float4*>(Wv1 + (size_t)t * DM),
                     reinterpret_cast<const float4*>(vbuf));
  } else if (bid == 229) {
    // ---------------- eo = Ebar @ Wout ----------------
    vbuf[t] = Wout[t];
    __syncthreads();
    {
      const int i = t >> 2, s = t & 3;
      float a = dot16f4(
          reinterpret_cast<const float4*>(Wemb + (size_t)i * DM + s * 64),
          reinterpret_cast<const float4*>(vbuf + s * 64));
      a += __shfl_down(a, 2); a += __shfl_down(a, 1);
      if (s == 0) eog[i] = a;
    }
    if (t < 64) {
      float p = dot4(*reinterpret_cast<const float4*>(bemb + t * 4),
                     *reinterpret_cast<const float4*>(vbuf + t * 4));
      p = wave_red(p);
      if (t == 0) eog[64] = p;
    }
    if (t >= 65 && t < 80) eog[t] = 0.f;
  } else {
    // ---------------- f0 = Ebar @ (Wv0 @ Wout) ----------------
    vbuf[t] = Wout[t];
    __syncthreads();
    a0s[t] = dot64f4(reinterpret_cast<const float4*>(Wv + (size_t)t * DM),
                     reinterpret_cast<const float4*>(vbuf));
    __syncthreads();
    {
      const int i = t >> 2, s = t & 3;
      float a = dot16f4(
          reinterpret_cast<const float4*>(Wemb + (size_t)i * DM + s * 64),
          reinterpret_cast<const float4*>(a0s + s * 64));
      a += __shfl_down(a, 2); a += __shfl_down(a, 1);
      if (s == 0) f0g[i] = a;
    }
    if (t < 64) {
      float p = dot4(*reinterpret_cast<const float4*>(bemb + t * 4),
                     *reinterpret_cast<const float4*>(a0s + t * 4));
      p = wave_red(p);
      if (t == 0) f0g[64] = p;
    }
    if (t >= 65 && t < 80) f0g[t] = 0.f;
  }
}

// ---------------------------------------------------------------------------
// K2 (4 blocks x 1024): per-batch chain, every dot 2-8-way lane-sliced.
// ---------------------------------------------------------------------------
__global__ __launch_bounds__(1024, 4)
void k_post(const float* __restrict__ Xp, const float* __restrict__ cp,
            const float* __restrict__ Et, const float* __restrict__ F0t,
            const float* __restrict__ Z0t, const float* __restrict__ Z1t,
            const float* __restrict__ Y1t, const float* __restrict__ Er,
            const float* __restrict__ F0r, const float* __restrict__ Z0r,
            const float* __restrict__ eog, const float* __restrict__ f0g,
            const float* __restrict__ w1g, const float* __restrict__ bout,
            float* __restrict__ out) {
  const int b = blockIdx.x, t = threadIdx.x;
  __shared__ __align__(16) float X[80][81];
  __shared__ __align__(16) float clp[4][64];
  __shared__ __align__(16) float w1l[256];
  __shared__ __align__(16) float cl[DP], eo[DP], f0[DP], e1[DP], f1[DP];
  __shared__ __align__(16) float al[256], z2[256], hv[256], t2[256];
  __shared__ __align__(16) float cM0[DP], y8[DP], g8[DP], qv[DP];
  __shared__ __align__(16) float rE[DP], rF[DP], t1v[DP], Xq[DP];
  __shared__ __align__(16) float pr0[DP], pr1[DP], pvq[DP];
  __shared__ float dots[3];

  // ---- P0: Xp reduce (16-deep), clp, stage w1l/eo/f0, X pads
  {
    const int e = t * 4;
    const float* base = Xp + (size_t)b * NCH * 4096 + e;
    float4 a0 = make_float4(0.f, 0.f, 0.f, 0.f), a1 = a0, a2 = a0, a3 = a0;
#pragma unroll
    for (int ch = 0; ch < NCH; ch += 4) {
      const float4 p0 = *reinterpret_cast<const float4*>(base + (size_t)ch * 4096);
      const float4 p1 = *reinterpret_cast<const float4*>(base + (size_t)(ch + 1) * 4096);
      const float4 p2 = *reinterpret_cast<const float4*>(base + (size_t)(ch + 2) * 4096);
      const float4 p3 = *reinterpret_cast<const float4*>(base + (size_t)(ch + 3) * 4096);
      a0.x += p0.x; a0.y += p0.y; a0.z += p0.z; a0.w += p0.w;
      a1.x += p1.x; a1.y += p1.y; a1.z += p1.z; a1.w += p1.w;
      a2.x += p2.x; a2.y += p2.y; a2.z += p2.z; a2.w += p2.w;
      a3.x += p3.x; a3.y += p3.y; a3.z += p3.z; a3.w += p3.w;
    }
    const float4 s = make_float4((a0.x + a1.x) + (a2.x + a3.x),
                                 (a0.y + a1.y) + (a2.y + a3.y),
                                 (a0.z + a1.z) + (a2.z + a3.z),
                                 (a0.w + a1.w) + (a2.w + a3.w));
    const int r = t >> 4, c = (t & 15) * 4;
    X[r][c] = s.x; X[r][c + 1] = s.y; X[r][c + 2] = s.z; X[r][c + 3] = s.w;

    if (t < 256) {
      const int si = t >> 6, i = t & 63;
      float v = 0.f;
#pragma unroll
      for (int c2 = 0; c2 < 4; ++c2)
        v += cp[(size_t)(b * NCH + si * 4 + c2) * 64 + i];
      clp[si][i] = v;
    } else if (t < 512) w1l[t - 256] = w1g[t - 256];
    else if (t < 592) eo[t - 512] = eog[t - 512];
    else if (t < 672) f0[t - 592] = f0g[t - 592];
    if (t >= 672) {
      for (int n = t - 672; n < 2255; n += 352) {
        if (n < 1040) X[n >> 4][65 + (n & 15)] = 0.f;
        else { const int m = n - 1040; X[65 + m / 81][m % 81] = 0.f; }
      }
    }
  }
  __syncthreads();

  // ---- P1: cl finalize || e1 = Ebar @ w1
  if (t < 64) cl[t] = (clp[0][t] + clp[1][t]) + (clp[2][t] + clp[3][t]);
  else if (t == 64) cl[64] = (float)SEQ;
  else if (t < 80) cl[t] = 0.f;
  else if (t >= 128 && t < 448) er4(Er, w1l, e1, t - 128, nullptr, 0.f);
  __syncthreads();

  // ---- P2: al = cbar @ Z0 || X borders || f1 = F0bar @ w1
  if (t < 512) {
    const int j = t >> 1, s = t & 1;
    float a = rd65h(Z0t + (size_t)j * DP, cl, s);
    a += __shfl_down(a, 1);
    if (s == 0) al[j] = a;
  } else if (t < 641) {
    const int n = t - 512;
    if (n < 64) X[n][64] = cl[n];
    else if (n == 64) X[64][64] = (float)SEQ;
    else X[64][n - 65] = cl[n - 65];
  } else if (t >= 704) er4(F0r, w1l, f1, t - 704, nullptr, 0.f);
  __syncthreads();

  // ---- S2: cM0 = al @ Ebar^T || y = Xbar f1
  if (t < 640) er8(Er, al, cM0, t);
  else if (t < 960) {
    const int u = t - 640, i = u >> 2, s = u & 3;
    float a = 0.f;
    for (int j = s * 20; j < s * 20 + 20; ++j) a += X[i][j] * f1[j];
    a += __shfl_down(a, 2); a += __shfl_down(a, 1);
    if (s == 0) y8[i] = a;
  }
  __syncthreads();

  // ---- S3: g = cM0 Xbar || z2 = y @ Ebar
  if (t < 320) {
    const int j = t >> 2, s = t & 3;
    float a = 0.f;
    for (int i = s * 20; i < s * 20 + 20; ++i) a += cM0[i] * X[i][j];
    a += __shfl_down(a, 2); a += __shfl_down(a, 1);
    if (s == 0) g8[j] = a;
  } else if (t < 832) {
    const int u = t - 320, j = u >> 1, s = u & 1;
    float a = rd65h(Et + (size_t)j * DP, y8, s);
    a += __shfl_down(a, 1);
    if (s == 0) z2[j] = a;
  }
  __syncthreads();

  // ---- S4: hv = cbar@Z1 + a*(g@Y1)
  {
    const int j = t >> 2, s = t & 3;
    float a = (s < 2) ? rd65h(Z1t + (size_t)j * DP, cl, s)
                      : rd65h(Y1t + (size_t)j * DP, g8, s - 2);
    a += __shfl_down(a, 1);
    const float yv = __shfl_down(a, 2);
    if (s == 0) hv[j] = a + ALPHA * yv;
  }
  __syncthreads();

  // ---- S5: rE = hv@Ebar^T || rF = hv@F0^T || qv = e1 + a*(z2@Z0^T)
  if (t < 320) er4(Er, hv, rE, t, nullptr, 0.f);
  else if (t < 640) er4(F0r, hv, rF, t - 320, nullptr, 0.f);
  else if (t < 960) er4(Z0r, z2, qv, t - 640, e1, ALPHA);
  __syncthreads();

  // ---- S6: t1 = rF Xbar || Xq = Xbar qv || pr0, pr1
  if (t < 320) {
    const int j = t >> 2, s = t & 3;
    float a = 0.f;
    for (int i = s * 20; i < s * 20 + 20; ++i) a += rF[i] * X[i][j];
    a += __shfl_down(a, 2); a += __shfl_down(a, 1);
    if (s == 0) t1v[j] = a;
  } else if (t < 640) {
    const int u = t - 320, i = u >> 2, s = u & 3;
    float a = 0.f;
    for (int j = s * 20; j < s * 20 + 20; ++j) a += X[i][j] * qv[j];
    a += __shfl_down(a, 2); a += __shfl_down(a, 1);
    if (s == 0) Xq[i] = a;
  } else if (t < 720) { const int i = t - 640; pr0[i] = cl[i] * eo[i]; }
  else if (t < 800) { const int i = t - 720; pr1[i] = g8[i] * f0[i]; }
  __syncthreads();

  // ---- S7: t2 = t1 @ Ebar
  {
    const int j = t >> 2, s = t & 3;
    float a = rd65q(Et + (size_t)j * DP, t1v, s);
    a += __shfl_down(a, 2); a += __shfl_down(a, 1);
    if (s == 0) t2[j] = a;
  }
  __syncthreads();

  // ---- S8: pvq = (rE + a*(t2@Z0^T)) * Xq
  if (t < 640) {
    const int i = t >> 3, s = t & 7;
    float a = dot8f4(reinterpret_cast<const float4*>(Z0r + (size_t)i * DM + s * 32),
                     reinterpret_cast<const float4*>(t2 + s * 32));
    a += __shfl_down(a, 4); a += __shfl_down(a, 2); a += __shfl_down(a, 1);
    if (s == 0) pvq[i] = (rE[i] + ALPHA * a) * Xq[i];
  }
  __syncthreads();

  // ---- S9: three 80-dots + out
  const int w = t >> 6, l = t & 63;
  if (w < 3) {
    const float* pr = (w == 0) ? pr0 : (w == 1) ? pr1 : pvq;
    float v = pr[l] + ((l < 16) ? pr[64 + l] : 0.f);
    v = wave_red(v);
    if (l == 0) dots[w] = v;
  }
  __syncthreads();
  if (t == 0) out[b] = dots[0] + ALPHA * dots[1] + ALPHA * dots[2] + bout[0];
}

}  // namespace

extern "C" void kernel_launch(void* const* d_in, const int* in_sizes, int n_in,
                              void* d_out, int out_size, void* d_ws, size_t ws_size,
                              hipStream_t stream) {
  const float* x    = (const float*)d_in[0];
  const float* Wemb = (const float*)d_in[1];
  const float* bemb = (const float*)d_in[2];
  const float* Wq   = (const float*)d_in[3];
  const float* Wk   = (const float*)d_in[4];
  const float* Wv   = (const float*)d_in[5];
  const float* Wout = (const float*)d_in[6];
  const float* bout = (const float*)d_in[7];
  float* out = (float*)d_out;

  float* p = (float*)d_ws;
  float* Xp  = p; p += (size_t)BATCH * NCH * 4096;
  float* cp  = p; p += (size_t)BATCH * NCH * 64;
  float* Z0t = p; p += 256 * DP;
  float* Z1t = p; p += 256 * DP;
  float* Y1t = p; p += 256 * DP;
  float* F0t = p; p += 256 * DP;
  float* Et  = p; p += 256 * DP;
  float* Er  = p; p += DP * 256;
  float* F0r = p; p += DP * 256;
  float* Z0r = p; p += DP * 256;
  float* w1g = p; p += 256;
  float* eog = p; p += 80;
  float* f0g = p; p += 80;

  const int nblk = 99 + BATCH * NCH * 2 + 4;  // 231
  k_pre<<<nblk, 256, 0, stream>>>(x, Wemb, bemb, Wq, Wk, Wv, Wout,
                                  Xp, cp, Z0t, Z1t, Y1t, F0t, Et, Er, F0r, Z0r,
                                  w1g, eog, f0g);
  k_post<<<BATCH, 1024, 0, stream>>>(Xp, cp, Et, F0t, Z0t, Z1t, Y1t, Er, F0r,
                                     Z0r, eog, f0g, w1g, bout, out);
}

// Round 8
// 41.177 us; speedup vs baseline: 2.8220x; 1.2743x over previous
//
#include <hip/hip_runtime.h>

namespace {

constexpr int BATCH = 4, SEQ = 4096, DM = 256, DP = 80, NCH = 16;
constexpr float ALPHA = 0.1f;

__device__ __forceinline__ float dot4(float4 a, float4 b) {
  return a.x * b.x + a.y * b.y + a.z * b.z + a.w * b.w;
}
__device__ __forceinline__ float dot5f4(const float* __restrict__ r,
                                        const float* v) {
  const float4* R = reinterpret_cast<const float4*>(r);
  const float4* V = reinterpret_cast<const float4*>(v);
  return ((dot4(R[0], V[0]) + dot4(R[1], V[1])) +
          (dot4(R[2], V[2]) + dot4(R[3], V[3]))) + dot4(R[4], V[4]);
}
__device__ __forceinline__ float dot10f4(const float* __restrict__ r,
                                         const float* v) {
  const float4* R = reinterpret_cast<const float4*>(r);
  const float4* V = reinterpret_cast<const float4*>(v);
  float a0 = 0.f, a1 = 0.f;
#pragma unroll
  for (int q = 0; q < 10; q += 2) {
    a0 += dot4(R[q], V[q]); a1 += dot4(R[q + 1], V[q + 1]);
  }
  return a0 + a1;
}
__device__ __forceinline__ float dot16f4(const float4* __restrict__ R,
                                         const float4* V) {
  float a0 = 0.f, a1 = 0.f, a2 = 0.f, a3 = 0.f;
#pragma unroll
  for (int q = 0; q < 16; q += 4) {
    a0 += dot4(R[q + 0], V[q + 0]); a1 += dot4(R[q + 1], V[q + 1]);
    a2 += dot4(R[q + 2], V[q + 2]); a3 += dot4(R[q + 3], V[q + 3]);
  }
  return (a0 + a1) + (a2 + a3);
}
__device__ __forceinline__ float dot32f4(const float* __restrict__ r,
                                         const float* v) {
  const float4* R = reinterpret_cast<const float4*>(r);
  const float4* V = reinterpret_cast<const float4*>(v);
  return dot16f4(R, V) + dot16f4(R + 16, V + 16);
}
__device__ __forceinline__ float dot64f4(const float* __restrict__ r,
                                         const float* v) {
  const float4* R = reinterpret_cast<const float4*>(r);
  const float4* V = reinterpret_cast<const float4*>(v);
  float a0 = 0.f, a1 = 0.f, a2 = 0.f, a3 = 0.f;
#pragma unroll 16
  for (int q = 0; q < 64; q += 4) {
    a0 += dot4(R[q + 0], V[q + 0]); a1 += dot4(R[q + 1], V[q + 1]);
    a2 += dot4(R[q + 2], V[q + 2]); a3 += dot4(R[q + 3], V[q + 3]);
  }
  return (a0 + a1) + (a2 + a3);
}
__device__ __forceinline__ float wave_red(float s) {
  s += __shfl_down(s, 32); s += __shfl_down(s, 16); s += __shfl_down(s, 8);
  s += __shfl_down(s, 4);  s += __shfl_down(s, 2);  s += __shfl_down(s, 1);
  return s;
}
// 256-term row dot, 4-way sliced; dst[i] = dot(Mr row i, v)
__device__ __forceinline__ void er4(const float* __restrict__ Mr,
                                    const float* v, float* dst, int u) {
  const int i = u >> 2, s = u & 3;
  float a = dot16f4(reinterpret_cast<const float4*>(Mr + (size_t)i * DM + s * 64),
                    reinterpret_cast<const float4*>(v + s * 64));
  a += __shfl_down(a, 2); a += __shfl_down(a, 1);
  if (s == 0) dst[i] = a;
}

// ---------------------------------------------------------------------------
// K1 roles: [0,33) Y1r(+F0), [33,66) Z0r, [66,99) Z1r, [99,227) x^T x,
// 227 Er build+pads, 228 w1, 229 eo, 230 f0.
// ---------------------------------------------------------------------------
__global__ __launch_bounds__(256, 2)
void k_pre(const float* __restrict__ x, const float* __restrict__ Wemb,
           const float* __restrict__ bemb, const float* __restrict__ Wq,
           const float* __restrict__ Wk, const float* __restrict__ Wv,
           const float* __restrict__ Wout,
           float* __restrict__ Xp, float* __restrict__ cp,
           float* __restrict__ Er, float* __restrict__ F0r,
           float* __restrict__ Z0r, float* __restrict__ Z1r,
           float* __restrict__ Y1r, float* __restrict__ w1g,
           float* __restrict__ eog, float* __restrict__ f0g) {
  const int bid = blockIdx.x, t = threadIdx.x;
  __shared__ __align__(16) float esT[512];
  __shared__ __align__(16) float fsT[512];
  __shared__ __align__(16) float psT[512];
  __shared__ __align__(16) float4 ppA[4][64];
  __shared__ __align__(16) float4 ppB[4][64];
  __shared__ __align__(16) float xs[2][16][64];
  __shared__ __align__(16) float cs[16][64];
  __shared__ __align__(16) float vbuf[256];
  __shared__ __align__(16) float a0s[256];

  if (bid < 99) {
    const int role = bid / 33, grp = bid % 33;   // 0:Y1 1:Z0 2:Z1
    const int r0 = grp * 2, nr = (r0 == 64) ? 1 : 2;
    {
      const float v0 = (r0 < 64) ? Wemb[(size_t)r0 * DM + t] : bemb[t];
      float v1 = 0.f;
      if (nr == 2) v1 = (r0 + 1 < 64) ? Wemb[(size_t)(r0 + 1) * DM + t] : bemb[t];
      esT[t * 2] = v0; esT[t * 2 + 1] = v1;
    }
    __syncthreads();
    const int jg = t & 63, ks = t >> 6, j0 = jg * 4;

    auto nt_pass = [&](const float* src, const float* __restrict__ M,
                       float* dstT, bool f0st) {
      float4 A0 = make_float4(0.f, 0.f, 0.f, 0.f);
      float4 A1 = make_float4(0.f, 0.f, 0.f, 0.f);
      const float* Mp = M + (size_t)(ks * 64) * DM + j0;
#pragma unroll 16
      for (int i = 0; i < 64; ++i) {
        const float4 m = *reinterpret_cast<const float4*>(Mp + (size_t)i * DM);
        const float s0 = src[(ks * 64 + i) * 2];
        const float s1 = src[(ks * 64 + i) * 2 + 1];
        A0.x += s0 * m.x; A0.y += s0 * m.y; A0.z += s0 * m.z; A0.w += s0 * m.w;
        A1.x += s1 * m.x; A1.y += s1 * m.y; A1.z += s1 * m.z; A1.w += s1 * m.w;
      }
      ppA[ks][jg] = A0; ppB[ks][jg] = A1;
      __syncthreads();
      if (t < 128) {
        const int rr = t >> 6, jj = t & 63;
        float4 q0, q1, q2, q3;
        if (rr == 0) { q0 = ppA[0][jj]; q1 = ppA[1][jj]; q2 = ppA[2][jj]; q3 = ppA[3][jj]; }
        else         { q0 = ppB[0][jj]; q1 = ppB[1][jj]; q2 = ppB[2][jj]; q3 = ppB[3][jj]; }
        const float4 s = make_float4((q0.x + q1.x) + (q2.x + q3.x),
                                     (q0.y + q1.y) + (q2.y + q3.y),
                                     (q0.z + q1.z) + (q2.z + q3.z),
                                     (q0.w + q1.w) + (q2.w + q3.w));
        dstT[(jj * 4 + 0) * 2 + rr] = s.x;
        dstT[(jj * 4 + 1) * 2 + rr] = s.y;
        dstT[(jj * 4 + 2) * 2 + rr] = s.z;
        dstT[(jj * 4 + 3) * 2 + rr] = s.w;
        if (f0st && rr < nr)
          *reinterpret_cast<float4*>(&F0r[(size_t)(r0 + rr) * DM + jj * 4]) = s;
      }
      __syncthreads();
    };

    const float* src2 = esT;
    const float* M1; const float* M2; float* dstR;
    if (role == 0) {
      nt_pass(esT, Wv, fsT, true);            // F0 = Ebar @ Wv0
      src2 = fsT;
      M1 = Wq + (size_t)DM * DM; M2 = Wk + (size_t)DM * DM; dstR = Y1r;
    } else if (role == 1) {
      M1 = Wq; M2 = Wk; dstR = Z0r;
    } else {
      M1 = Wq + (size_t)DM * DM; M2 = Wk + (size_t)DM * DM; dstR = Z1r;
    }
    nt_pass(src2, M1, psT, false);

    {  // TN: dstR[r][j] = sum_k p[k][r] * M2[j][k]
      const int j = t;
      const float4* Mrow = reinterpret_cast<const float4*>(M2 + (size_t)j * DM);
      float ac0 = 0.f, ac1 = 0.f;
#pragma unroll 16
      for (int u = 0; u < 64; ++u) {
        const float4 m = Mrow[u];
        const int k4 = u * 4;
        ac0 += (m.x * psT[(k4 + 0) * 2] + m.y * psT[(k4 + 1) * 2]) +
               (m.z * psT[(k4 + 2) * 2] + m.w * psT[(k4 + 3) * 2]);
        ac1 += (m.x * psT[(k4 + 0) * 2 + 1] + m.y * psT[(k4 + 1) * 2 + 1]) +
               (m.z * psT[(k4 + 2) * 2 + 1] + m.w * psT[(k4 + 3) * 2 + 1]);
      }
      dstR[(size_t)r0 * DM + j] = ac0;
      if (nr == 2) dstR[(size_t)(r0 + 1) * DM + j] = ac1;
    }
  } else if (bid < 227) {
    // ---------------- x^T x partials (double-buffered, col-halved) --------
    const int idx = bid - 99;
    const int per_b = NCH * 2;
    const int b = idx / per_b, r5 = idx % per_b, ch = r5 >> 1, half = r5 & 1;
    const int chrows = SEQ / NCH, nstage = chrows / 16;
    const float* xb = x + ((size_t)b * SEQ + (size_t)ch * chrows) * 64;
    const int trs = t >> 4, tcs = t & 15;
    const int tr2 = t >> 3, tc2 = t & 7;

    float acc[2][4] = {{0.f, 0.f, 0.f, 0.f}, {0.f, 0.f, 0.f, 0.f}};
    float4 csum = make_float4(0.f, 0.f, 0.f, 0.f);
    float4 v = *reinterpret_cast<const float4*>(xb + (size_t)trs * 64 + tcs * 4);
    int buf = 0;
    for (int st = 0; st < nstage; ++st) {
      *reinterpret_cast<float4*>(&xs[buf][trs][tcs * 4]) = v;
      csum.x += v.x; csum.y += v.y; csum.z += v.z; csum.w += v.w;
      __syncthreads();
      float4 vn = make_float4(0.f, 0.f, 0.f, 0.f);
      if (st + 1 < nstage)
        vn = *reinterpret_cast<const float4*>(
            xb + (size_t)((st + 1) * 16 + trs) * 64 + tcs * 4);
#pragma unroll
      for (int s = 0; s < 16; ++s) {
        const float a0 = xs[buf][s][tr2 * 2 + 0];
        const float a1 = xs[buf][s][tr2 * 2 + 1];
        const float4 b4 =
            *reinterpret_cast<const float4*>(&xs[buf][s][half * 32 + tc2 * 4]);
        acc[0][0] += a0 * b4.x; acc[0][1] += a0 * b4.y;
        acc[0][2] += a0 * b4.z; acc[0][3] += a0 * b4.w;
        acc[1][0] += a1 * b4.x; acc[1][1] += a1 * b4.y;
        acc[1][2] += a1 * b4.z; acc[1][3] += a1 * b4.w;
      }
      v = vn; buf ^= 1;
    }
    float* Xpb = Xp + (size_t)(b * NCH + ch) * 4096;
#pragma unroll
    for (int rr = 0; rr < 2; ++rr) {
      const float4 s4 = make_float4(acc[rr][0], acc[rr][1], acc[rr][2], acc[rr][3]);
      *reinterpret_cast<float4*>(
          &Xpb[(size_t)(tr2 * 2 + rr) * 64 + half * 32 + tc2 * 4]) = s4;
    }
    if (half == 0) {
      *reinterpret_cast<float4*>(&cs[trs][tcs * 4]) = csum;
      __syncthreads();
      if (t < 64) {
        float s = 0.f;
#pragma unroll
        for (int g = 0; g < 16; ++g) s += cs[g][t];
        cp[(size_t)(b * NCH + ch) * 64 + t] = s;
      }
    }
  } else if (bid == 227) {
    // ---------------- Er build + pad-row zeroing ----------------
    for (int i = 0; i < 64; ++i)
      Er[(size_t)i * DM + t] = Wemb[(size_t)i * DM + t];
    Er[(size_t)64 * DM + t] = bemb[t];
    for (int i = 65; i < DP; ++i) {
      Er[(size_t)i * DM + t] = 0.f;
      F0r[(size_t)i * DM + t] = 0.f;
      Z0r[(size_t)i * DM + t] = 0.f;
      Z1r[(size_t)i * DM + t] = 0.f;
      Y1r[(size_t)i * DM + t] = 0.f;
    }
  } else if (bid == 228) {
    vbuf[t] = Wout[t];
    __syncthreads();
    const float* Wv1 = Wv + (size_t)DM * DM;
    w1g[t] = dot64f4(Wv1 + (size_t)t * DM, vbuf);
  } else if (bid == 229) {
    vbuf[t] = Wout[t];
    __syncthreads();
    {
      const int i = t >> 2, s = t & 3;
      float a = dot16f4(
          reinterpret_cast<const float4*>(Wemb + (size_t)i * DM + s * 64),
          reinterpret_cast<const float4*>(vbuf + s * 64));
      a += __shfl_down(a, 2); a += __shfl_down(a, 1);
      if (s == 0) eog[i] = a;
    }
    if (t < 64) {
      float p = dot4(*reinterpret_cast<const float4*>(bemb + t * 4),
                     *reinterpret_cast<const float4*>(vbuf + t * 4));
      p = wave_red(p);
      if (t == 0) eog[64] = p;
    }
    if (t >= 65 && t < 80) eog[t] = 0.f;
  } else {
    vbuf[t] = Wout[t];
    __syncthreads();
    a0s[t] = dot64f4(Wv + (size_t)t * DM, vbuf);
    __syncthreads();
    {
      const int i = t >> 2, s = t & 3;
      float a = dot16f4(
          reinterpret_cast<const float4*>(Wemb + (size_t)i * DM + s * 64),
          reinterpret_cast<const float4*>(a0s + s * 64));
      a += __shfl_down(a, 2); a += __shfl_down(a, 1);
      if (s == 0) f0g[i] = a;
    }
    if (t < 64) {
      float p = dot4(*reinterpret_cast<const float4*>(bemb + t * 4),
                     *reinterpret_cast<const float4*>(a0s + t * 4));
      p = wave_red(p);
      if (t == 0) f0g[64] = p;
    }
    if (t >= 65 && t < 80) f0g[t] = 0.f;
  }
}

// ---------------------------------------------------------------------------
// K_mid (400 blocks): composite 80x80 matrices.
//  mat 0: C0[j][i]=dot(Z0r_i,Er_j) (+C0T) ; 1: C1=Z1r.Er ; 2: CY=Y1r.Er ;
//  3: D1=Z1r.F0r ; 4: DY=Y1r.F0r.
// ---------------------------------------------------------------------------
__global__ __launch_bounds__(256, 2)
void k_mid(const float* __restrict__ Er, const float* __restrict__ F0r,
           const float* __restrict__ Z0r, const float* __restrict__ Z1r,
           const float* __restrict__ Y1r,
           float* __restrict__ C0, float* __restrict__ C0T,
           float* __restrict__ C1, float* __restrict__ CY,
           float* __restrict__ D1, float* __restrict__ DY) {
  const int bid = blockIdx.x, t = threadIdx.x;
  const int mat = bid / 80, j = bid % 80;
  __shared__ __align__(16) float bvs[256];
  const float* bsrc = (mat < 3) ? Er : F0r;
  bvs[t] = bsrc[(size_t)j * DM + t];
  __syncthreads();
  if (t < 160) {
    const int i = t >> 1, s = t & 1;
    const float* A = (mat == 0) ? Z0r : (mat == 1 || mat == 3) ? Z1r : Y1r;
    float a = dot32f4(A + (size_t)i * DM + s * 128, bvs + s * 128);
    a += __shfl_down(a, 1);
    if (s == 0) {
      if (mat == 0) { C0[j * DP + i] = a; C0T[i * DP + j] = a; }
      else if (mat == 1) C1[j * DP + i] = a;
      else if (mat == 2) CY[j * DP + i] = a;
      else if (mat == 3) D1[j * DP + i] = a;
      else DY[j * DP + i] = a;
    }
  }
}

// ---------------------------------------------------------------------------
// K_post (4 blocks x 1024): 8-step chain in 80-dim space.
// ---------------------------------------------------------------------------
__global__ __launch_bounds__(1024, 4)
void k_post(const float* __restrict__ Xp, const float* __restrict__ cp,
            const float* __restrict__ Er, const float* __restrict__ F0r,
            const float* __restrict__ C0, const float* __restrict__ C0T,
            const float* __restrict__ C1, const float* __restrict__ CY,
            const float* __restrict__ D1, const float* __restrict__ DY,
            const float* __restrict__ eog, const float* __restrict__ f0g,
            const float* __restrict__ w1g, const float* __restrict__ bout,
            float* __restrict__ out) {
  const int b = blockIdx.x, t = threadIdx.x;
  __shared__ __align__(16) float X[80][81];
  __shared__ __align__(16) float clp[4][64];
  __shared__ __align__(16) float w1l[256];
  __shared__ __align__(16) float cl[DP], eo[DP], f0[DP], e1[DP], f1[DP];
  __shared__ __align__(16) float cM0[DP], g8[DP], y8[DP], qv[DP];
  __shared__ __align__(16) float rE[DP], rF[DP], t1v[DP], Xq[DP];
  __shared__ __align__(16) float pr0[DP], pr1[DP], pr2[DP];
  __shared__ float dots[3];

  // ---- P0: X core reduce + clp + staging + X pads
  {
    const int e = t * 4;
    const float* base = Xp + (size_t)b * NCH * 4096 + e;
    float4 a0 = make_float4(0.f, 0.f, 0.f, 0.f), a1 = a0, a2 = a0, a3 = a0;
#pragma unroll
    for (int ch = 0; ch < NCH; ch += 4) {
      const float4 p0 = *reinterpret_cast<const float4*>(base + (size_t)ch * 4096);
      const float4 p1 = *reinterpret_cast<const float4*>(base + (size_t)(ch + 1) * 4096);
      const float4 p2 = *reinterpret_cast<const float4*>(base + (size_t)(ch + 2) * 4096);
      const float4 p3 = *reinterpret_cast<const float4*>(base + (size_t)(ch + 3) * 4096);
      a0.x += p0.x; a0.y += p0.y; a0.z += p0.z; a0.w += p0.w;
      a1.x += p1.x; a1.y += p1.y; a1.z += p1.z; a1.w += p1.w;
      a2.x += p2.x; a2.y += p2.y; a2.z += p2.z; a2.w += p2.w;
      a3.x += p3.x; a3.y += p3.y; a3.z += p3.z; a3.w += p3.w;
    }
    const float4 s = make_float4((a0.x + a1.x) + (a2.x + a3.x),
                                 (a0.y + a1.y) + (a2.y + a3.y),
                                 (a0.z + a1.z) + (a2.z + a3.z),
                                 (a0.w + a1.w) + (a2.w + a3.w));
    const int r = t >> 4, c = (t & 15) * 4;
    X[r][c] = s.x; X[r][c + 1] = s.y; X[r][c + 2] = s.z; X[r][c + 3] = s.w;

    if (t < 256) {
      const int si = t >> 6, i = t & 63;
      float v = 0.f;
#pragma unroll
      for (int c2 = 0; c2 < 4; ++c2)
        v += cp[(size_t)(b * NCH + si * 4 + c2) * 64 + i];
      clp[si][i] = v;
    } else if (t < 512) w1l[t - 256] = w1g[t - 256];
    else if (t < 592) eo[t - 512] = eog[t - 512];
    else if (t < 672) f0[t - 592] = f0g[t - 592];
    if (t >= 672) {
      for (int n = t - 672; n < 2255; n += 352) {
        if (n < 1040) X[n >> 4][65 + (n & 15)] = 0.f;
        else { const int m = n - 1040; X[65 + m / 81][m % 81] = 0.f; }
      }
    }
  }
  __syncthreads();

  // ---- P1: cl finalize || e1 = Er@w1 || f1 = F0r@w1
  if (t < 64) cl[t] = (clp[0][t] + clp[1][t]) + (clp[2][t] + clp[3][t]);
  else if (t == 64) cl[64] = (float)SEQ;
  else if (t < 80) cl[t] = 0.f;
  else if (t >= 128 && t < 448) er4(Er, w1l, e1, t - 128);
  else if (t >= 448 && t < 768) er4(F0r, w1l, f1, t - 448);
  __syncthreads();

  // ---- S1: cM0 = C0·cl || X borders || pr0 = cl*eo
  if (t < 320) {
    const int j = t >> 2, s = t & 3;
    float a = dot5f4(C0 + j * DP + s * 20, cl + s * 20);
    a += __shfl_down(a, 2); a += __shfl_down(a, 1);
    if (s == 0) cM0[j] = a;
  } else if (t >= 384 && t < 513) {
    const int n = t - 384;
    if (n < 64) X[n][64] = cl[n];
    else if (n == 64) X[64][64] = (float)SEQ;
    else X[64][n - 65] = cl[n - 65];
  } else if (t >= 576 && t < 656) {
    const int i = t - 576; pr0[i] = cl[i] * eo[i];
  }
  __syncthreads();

  // ---- S2 (LDS): g = cM0·X || y = X·f1
  if (t < 320) {
    const int j = t >> 2, s = t & 3;
    float a = 0.f;
    for (int i = s * 20; i < s * 20 + 20; ++i) a += cM0[i] * X[i][j];
    a += __shfl_down(a, 2); a += __shfl_down(a, 1);
    if (s == 0) g8[j] = a;
  } else if (t < 640) {
    const int u = t - 320, i = u >> 2, s = u & 3;
    float a = 0.f;
    for (int j = s * 20; j < s * 20 + 20; ++j) a += X[i][j] * f1[j];
    a += __shfl_down(a, 2); a += __shfl_down(a, 1);
    if (s == 0) y8[i] = a;
  }
  __syncthreads();

  // ---- S3: rE = C1·cl + a·CY·g || rF = D1·cl + a·DY·g || qv = e1 + a·C0T·y
  if (t < 320) {
    const int j = t >> 2, s = t & 3;
    float a = (s < 2) ? dot10f4(C1 + j * DP + s * 40, cl + s * 40)
                      : ALPHA * dot10f4(CY + j * DP + (s - 2) * 40, g8 + (s - 2) * 40);
    a += __shfl_down(a, 2); a += __shfl_down(a, 1);
    if (s == 0) rE[j] = a;
  } else if (t < 640) {
    const int u = t - 320, j = u >> 2, s = u & 3;
    float a = (s < 2) ? dot10f4(D1 + j * DP + s * 40, cl + s * 40)
                      : ALPHA * dot10f4(DY + j * DP + (s - 2) * 40, g8 + (s - 2) * 40);
    a += __shfl_down(a, 2); a += __shfl_down(a, 1);
    if (s == 0) rF[j] = a;
  } else if (t < 960) {
    const int u = t - 640, j = u >> 2, s = u & 3;
    float a = dot5f4(C0T + j * DP + s * 20, y8 + s * 20);
    a += __shfl_down(a, 2); a += __shfl_down(a, 1);
    if (s == 0) qv[j] = e1[j] + ALPHA * a;
  }
  __syncthreads();

  // ---- S4 (LDS): t1 = rF·X || Xq = X·qv || pr1 = g*f0
  if (t < 320) {
    const int j = t >> 2, s = t & 3;
    float a = 0.f;
    for (int i = s * 20; i < s * 20 + 20; ++i) a += rF[i] * X[i][j];
    a += __shfl_down(a, 2); a += __shfl_down(a, 1);
    if (s == 0) t1v[j] = a;
  } else if (t < 640) {
    const int u = t - 320, i = u >> 2, s = u & 3;
    float a = 0.f;
    for (int j = s * 20; j < s * 20 + 20; ++j) a += X[i][j] * qv[j];
    a += __shfl_down(a, 2); a += __shfl_down(a, 1);
    if (s == 0) Xq[i] = a;
  } else if (t < 720) {
    const int i = t - 640; pr1[i] = g8[i] * f0[i];
  }
  __syncthreads();

  // ---- S5: pr2 = (rE + a·C0T·t1) * Xq
  if (t < 320) {
    const int j = t >> 2, s = t & 3;
    float a = dot5f4(C0T + j * DP + s * 20, t1v + s * 20);
    a += __shfl_down(a, 2); a += __shfl_down(a, 1);
    if (s == 0) pr2[j] = (rE[j] + ALPHA * a) * Xq[j];
  }
  __syncthreads();

  // ---- S6: three 80-dots + out
  const int w = t >> 6, l = t & 63;
  if (w < 3) {
    const float* pr = (w == 0) ? pr0 : (w == 1) ? pr1 : pr2;
    float v = pr[l] + ((l < 16) ? pr[64 + l] : 0.f);
    v = wave_red(v);
    if (l == 0) dots[w] = v;
  }
  __syncthreads();
  if (t == 0) out[b] = dots[0] + ALPHA * dots[1] + ALPHA * dots[2] + bout[0];
}

}  // namespace

extern "C" void kernel_launch(void* const* d_in, const int* in_sizes, int n_in,
                              void* d_out, int out_size, void* d_ws, size_t ws_size,
                              hipStream_t stream) {
  const float* x    = (const float*)d_in[0];
  const float* Wemb = (const float*)d_in[1];
  const float* bemb = (const float*)d_in[2];
  const float* Wq   = (const float*)d_in[3];
  const float* Wk   = (const float*)d_in[4];
  const float* Wv   = (const float*)d_in[5];
  const float* Wout = (const float*)d_in[6];
  const float* bout = (const float*)d_in[7];
  float* out = (float*)d_out;

  float* p = (float*)d_ws;
  float* Xp  = p; p += (size_t)BATCH * NCH * 4096;
  float* cp  = p; p += (size_t)BATCH * NCH * 64;
  float* Er  = p; p += DP * 256;
  float* F0r = p; p += DP * 256;
  float* Z0r = p; p += DP * 256;
  float* Z1r = p; p += DP * 256;
  float* Y1r = p; p += DP * 256;
  float* w1g = p; p += 256;
  float* eog = p; p += 80;
  float* f0g = p; p += 80;
  float* C0  = p; p += DP * DP;
  float* C0T = p; p += DP * DP;
  float* C1  = p; p += DP * DP;
  float* CY  = p; p += DP * DP;
  float* D1  = p; p += DP * DP;
  float* DY  = p; p += DP * DP;

  k_pre<<<231, 256, 0, stream>>>(x, Wemb, bemb, Wq, Wk, Wv, Wout,
                                 Xp, cp, Er, F0r, Z0r, Z1r, Y1r,
                                 w1g, eog, f0g);
  k_mid<<<400, 256, 0, stream>>>(Er, F0r, Z0r, Z1r, Y1r,
                                 C0, C0T, C1, CY, D1, DY);
  k_post<<<BATCH, 1024, 0, stream>>>(Xp, cp, Er, F0r, C0, C0T, C1, CY, D1, DY,
                                     eog, f0g, w1g, bout, out);
}

// Round 9
// 33.159 us; speedup vs baseline: 3.5044x; 1.2418x over previous
//
#include <hip/hip_runtime.h>

namespace {

constexpr int BATCH = 4, SEQ = 4096, DM = 256, DP = 80, NCH = 16;
constexpr float ALPHA = 0.1f;

__device__ __forceinline__ float dot4(float4 a, float4 b) {
  return a.x * b.x + a.y * b.y + a.z * b.z + a.w * b.w;
}
__device__ __forceinline__ float dot5f4(const float* __restrict__ r,
                                        const float* v) {
  const float4* R = reinterpret_cast<const float4*>(r);
  const float4* V = reinterpret_cast<const float4*>(v);
  return ((dot4(R[0], V[0]) + dot4(R[1], V[1])) +
          (dot4(R[2], V[2]) + dot4(R[3], V[3]))) + dot4(R[4], V[4]);
}
__device__ __forceinline__ float dot10f4(const float* __restrict__ r,
                                         const float* v) {
  const float4* R = reinterpret_cast<const float4*>(r);
  const float4* V = reinterpret_cast<const float4*>(v);
  float a0 = 0.f, a1 = 0.f;
#pragma unroll
  for (int q = 0; q < 10; q += 2) {
    a0 += dot4(R[q], V[q]); a1 += dot4(R[q + 1], V[q + 1]);
  }
  return a0 + a1;
}
__device__ __forceinline__ float dot16f4(const float4* __restrict__ R,
                                         const float4* V) {
  float a0 = 0.f, a1 = 0.f, a2 = 0.f, a3 = 0.f;
#pragma unroll
  for (int q = 0; q < 16; q += 4) {
    a0 += dot4(R[q + 0], V[q + 0]); a1 += dot4(R[q + 1], V[q + 1]);
    a2 += dot4(R[q + 2], V[q + 2]); a3 += dot4(R[q + 3], V[q + 3]);
  }
  return (a0 + a1) + (a2 + a3);
}
__device__ __forceinline__ float dot32f4(const float* __restrict__ r,
                                         const float* v) {
  const float4* R = reinterpret_cast<const float4*>(r);
  const float4* V = reinterpret_cast<const float4*>(v);
  return dot16f4(R, V) + dot16f4(R + 16, V + 16);
}
__device__ __forceinline__ float dot64f4(const float* __restrict__ r,
                                         const float* v) {
  const float4* R = reinterpret_cast<const float4*>(r);
  const float4* V = reinterpret_cast<const float4*>(v);
  float a0 = 0.f, a1 = 0.f, a2 = 0.f, a3 = 0.f;
#pragma unroll 16
  for (int q = 0; q < 64; q += 4) {
    a0 += dot4(R[q + 0], V[q + 0]); a1 += dot4(R[q + 1], V[q + 1]);
    a2 += dot4(R[q + 2], V[q + 2]); a3 += dot4(R[q + 3], V[q + 3]);
  }
  return (a0 + a1) + (a2 + a3);
}
__device__ __forceinline__ float wave_red(float s) {
  s += __shfl_down(s, 32); s += __shfl_down(s, 16); s += __shfl_down(s, 8);
  s += __shfl_down(s, 4);  s += __shfl_down(s, 2);  s += __shfl_down(s, 1);
  return s;
}

// ---------------------------------------------------------------------------
// K1: [0,231) factor rows (7 roles x 33 groups); [231,359) x^T x partials;
//     359: eo = Ebar@Wout; 360: w1 = Wv1@Wout.
// Factors (row-major [80][256], pad rows zeroed):
//  role 0: F0 = Ebar@Wv0 ; 1: P0=Ebar@Wq0 ; 2: K0=Ebar@Wk0 ; 3: P1=Ebar@Wq1 ;
//  4: K1=Ebar@Wk1 ; 5: PF1=F0@Wq1 ; 6: KF1=F0@Wk1
// ---------------------------------------------------------------------------
__global__ __launch_bounds__(256, 2)
void k_pre(const float* __restrict__ x, const float* __restrict__ Wemb,
           const float* __restrict__ bemb, const float* __restrict__ Wq,
           const float* __restrict__ Wk, const float* __restrict__ Wv,
           const float* __restrict__ Wout,
           float* __restrict__ Xp, float* __restrict__ cp,
           float* __restrict__ F0r, float* __restrict__ P0r,
           float* __restrict__ K0r, float* __restrict__ P1r,
           float* __restrict__ K1r, float* __restrict__ PF1r,
           float* __restrict__ KF1r, float* __restrict__ w1g,
           float* __restrict__ eog) {
  const int bid = blockIdx.x, t = threadIdx.x;
  __shared__ __align__(16) float esT[512];
  __shared__ __align__(16) float fsT[512];
  __shared__ __align__(16) float psT[512];
  __shared__ __align__(16) float4 ppA[4][64];
  __shared__ __align__(16) float4 ppB[4][64];
  __shared__ __align__(16) float xs[2][16][64];
  __shared__ __align__(16) float cs[16][64];
  __shared__ __align__(16) float vbuf[256];

  if (bid < 231) {
    const int role = bid / 33, grp = bid % 33;
    const int r0 = grp * 2, nr = (r0 == 64) ? 1 : 2;
    {
      const float v0 = (r0 < 64) ? Wemb[(size_t)r0 * DM + t] : bemb[t];
      float v1 = 0.f;
      if (nr == 2) v1 = (r0 + 1 < 64) ? Wemb[(size_t)(r0 + 1) * DM + t] : bemb[t];
      esT[t * 2] = v0; esT[t * 2 + 1] = v1;
    }
    __syncthreads();
    const int jg = t & 63, ks = t >> 6, j0 = jg * 4;

    auto nt_pass = [&](const float* src, const float* __restrict__ M,
                       float* dstT, float* dstR) {
      float4 A0 = make_float4(0.f, 0.f, 0.f, 0.f);
      float4 A1 = make_float4(0.f, 0.f, 0.f, 0.f);
      const float* Mp = M + (size_t)(ks * 64) * DM + j0;
#pragma unroll 16
      for (int i = 0; i < 64; ++i) {
        const float4 m = *reinterpret_cast<const float4*>(Mp + (size_t)i * DM);
        const float s0 = src[(ks * 64 + i) * 2];
        const float s1 = src[(ks * 64 + i) * 2 + 1];
        A0.x += s0 * m.x; A0.y += s0 * m.y; A0.z += s0 * m.z; A0.w += s0 * m.w;
        A1.x += s1 * m.x; A1.y += s1 * m.y; A1.z += s1 * m.z; A1.w += s1 * m.w;
      }
      ppA[ks][jg] = A0; ppB[ks][jg] = A1;
      __syncthreads();
      if (t < 128) {
        const int rr = t >> 6, jj = t & 63;
        float4 q0, q1, q2, q3;
        if (rr == 0) { q0 = ppA[0][jj]; q1 = ppA[1][jj]; q2 = ppA[2][jj]; q3 = ppA[3][jj]; }
        else         { q0 = ppB[0][jj]; q1 = ppB[1][jj]; q2 = ppB[2][jj]; q3 = ppB[3][jj]; }
        const float4 s = make_float4((q0.x + q1.x) + (q2.x + q3.x),
                                     (q0.y + q1.y) + (q2.y + q3.y),
                                     (q0.z + q1.z) + (q2.z + q3.z),
                                     (q0.w + q1.w) + (q2.w + q3.w));
        if (dstT) {
          dstT[(jj * 4 + 0) * 2 + rr] = s.x;
          dstT[(jj * 4 + 1) * 2 + rr] = s.y;
          dstT[(jj * 4 + 2) * 2 + rr] = s.z;
          dstT[(jj * 4 + 3) * 2 + rr] = s.w;
        }
        if (dstR && rr < nr)
          *reinterpret_cast<float4*>(&dstR[(size_t)(r0 + rr) * DM + jj * 4]) = s;
      }
      __syncthreads();
    };

    const float* Wq1 = Wq + (size_t)DM * DM;
    const float* Wk1 = Wk + (size_t)DM * DM;
    float* dstR;
    if (role == 0)      { dstR = F0r;  nt_pass(esT, Wv,  nullptr, dstR); }
    else if (role == 1) { dstR = P0r;  nt_pass(esT, Wq,  nullptr, dstR); }
    else if (role == 2) { dstR = K0r;  nt_pass(esT, Wk,  nullptr, dstR); }
    else if (role == 3) { dstR = P1r;  nt_pass(esT, Wq1, nullptr, dstR); }
    else if (role == 4) { dstR = K1r;  nt_pass(esT, Wk1, nullptr, dstR); }
    else if (role == 5) {
      dstR = PF1r;
      nt_pass(esT, Wv, fsT, nullptr);
      nt_pass(fsT, Wq1, nullptr, dstR);
    } else {
      dstR = KF1r;
      nt_pass(esT, Wv, fsT, nullptr);
      nt_pass(fsT, Wk1, nullptr, dstR);
    }
    if (grp == 32) {  // zero pad rows 65..79 of this role's matrix
      for (int rr = 65; rr < DP; ++rr) dstR[(size_t)rr * DM + t] = 0.f;
    }
  } else if (bid < 359) {
    // ---------------- x^T x partials (double-buffered, col-halved) --------
    const int idx = bid - 231;
    const int per_b = NCH * 2;
    const int b = idx / per_b, r5 = idx % per_b, ch = r5 >> 1, half = r5 & 1;
    const int chrows = SEQ / NCH, nstage = chrows / 16;
    const float* xb = x + ((size_t)b * SEQ + (size_t)ch * chrows) * 64;
    const int trs = t >> 4, tcs = t & 15;
    const int tr2 = t >> 3, tc2 = t & 7;

    float acc[2][4] = {{0.f, 0.f, 0.f, 0.f}, {0.f, 0.f, 0.f, 0.f}};
    float4 csum = make_float4(0.f, 0.f, 0.f, 0.f);
    float4 v = *reinterpret_cast<const float4*>(xb + (size_t)trs * 64 + tcs * 4);
    int buf = 0;
    for (int st = 0; st < nstage; ++st) {
      *reinterpret_cast<float4*>(&xs[buf][trs][tcs * 4]) = v;
      csum.x += v.x; csum.y += v.y; csum.z += v.z; csum.w += v.w;
      __syncthreads();
      float4 vn = make_float4(0.f, 0.f, 0.f, 0.f);
      if (st + 1 < nstage)
        vn = *reinterpret_cast<const float4*>(
            xb + (size_t)((st + 1) * 16 + trs) * 64 + tcs * 4);
#pragma unroll
      for (int s = 0; s < 16; ++s) {
        const float a0 = xs[buf][s][tr2 * 2 + 0];
        const float a1 = xs[buf][s][tr2 * 2 + 1];
        const float4 b4 =
            *reinterpret_cast<const float4*>(&xs[buf][s][half * 32 + tc2 * 4]);
        acc[0][0] += a0 * b4.x; acc[0][1] += a0 * b4.y;
        acc[0][2] += a0 * b4.z; acc[0][3] += a0 * b4.w;
        acc[1][0] += a1 * b4.x; acc[1][1] += a1 * b4.y;
        acc[1][2] += a1 * b4.z; acc[1][3] += a1 * b4.w;
      }
      v = vn; buf ^= 1;
    }
    float* Xpb = Xp + (size_t)(b * NCH + ch) * 4096;
#pragma unroll
    for (int rr = 0; rr < 2; ++rr) {
      const float4 s4 = make_float4(acc[rr][0], acc[rr][1], acc[rr][2], acc[rr][3]);
      *reinterpret_cast<float4*>(
          &Xpb[(size_t)(tr2 * 2 + rr) * 64 + half * 32 + tc2 * 4]) = s4;
    }
    if (half == 0) {
      *reinterpret_cast<float4*>(&cs[trs][tcs * 4]) = csum;
      __syncthreads();
      if (t < 64) {
        float s = 0.f;
#pragma unroll
        for (int g = 0; g < 16; ++g) s += cs[g][t];
        cp[(size_t)(b * NCH + ch) * 64 + t] = s;
      }
    }
  } else if (bid == 359) {
    // ---------------- eo = Ebar @ Wout ----------------
    vbuf[t] = Wout[t];
    __syncthreads();
    if (t < 160) {
      const int i = t >> 1, s = t & 1;
      const float* row = (i < 64) ? Wemb + (size_t)i * DM : (i == 64) ? bemb : nullptr;
      float a = row ? dot32f4(row + s * 128, vbuf + s * 128) : 0.f;
      a += __shfl_down(a, 1);
      if (s == 0) eog[i] = a;
    }
  } else {
    // ---------------- w1 = Wv1 @ Wout ----------------
    vbuf[t] = Wout[t];
    __syncthreads();
    const float* Wv1 = Wv + (size_t)DM * DM;
    w1g[t] = dot64f4(Wv1 + (size_t)t * DM, vbuf);
  }
}

// ---------------------------------------------------------------------------
// K_mid (403 blocks): composites from factors + e1/f1/f0 vectors.
//  [0,400): mat = bid/80, j = bid%80:
//   0: C0[j][i]=P0_i.K0_j (+C0T) ; 1: C1=P1.K1 ; 2: CY=PF1.K1 ;
//   3: D1=P1.KF1 ; 4: DY=PF1.KF1
//  400: e1 = Ebar@w1 ; 401: f1 = F0@w1 ; 402: f0 = F0@Wout
// ---------------------------------------------------------------------------
__global__ __launch_bounds__(256, 2)
void k_mid(const float* __restrict__ Wemb, const float* __restrict__ bemb,
           const float* __restrict__ Wout,
           const float* __restrict__ F0r, const float* __restrict__ P0r,
           const float* __restrict__ K0r, const float* __restrict__ P1r,
           const float* __restrict__ K1r, const float* __restrict__ PF1r,
           const float* __restrict__ KF1r, const float* __restrict__ w1g,
           float* __restrict__ C0, float* __restrict__ C0T,
           float* __restrict__ C1, float* __restrict__ CY,
           float* __restrict__ D1, float* __restrict__ DY,
           float* __restrict__ e1g, float* __restrict__ f1g,
           float* __restrict__ f0g) {
  const int bid = blockIdx.x, t = threadIdx.x;
  __shared__ __align__(16) float bvs[256];
  if (bid < 400) {
    const int mat = bid / 80, j = bid % 80;
    const float* bsrc = (mat == 0) ? K0r : (mat < 3) ? K1r : KF1r;
    bvs[t] = bsrc[(size_t)j * DM + t];
    __syncthreads();
    if (t < 160) {
      const int i = t >> 1, s = t & 1;
      const float* A = (mat == 0) ? P0r : (mat == 1 || mat == 3) ? P1r : PF1r;
      float a = dot32f4(A + (size_t)i * DM + s * 128, bvs + s * 128);
      a += __shfl_down(a, 1);
      if (s == 0) {
        if (mat == 0) { C0[j * DP + i] = a; C0T[i * DP + j] = a; }
        else if (mat == 1) C1[j * DP + i] = a;
        else if (mat == 2) CY[j * DP + i] = a;
        else if (mat == 3) D1[j * DP + i] = a;
        else DY[j * DP + i] = a;
      }
    }
  } else {
    const int which = bid - 400;  // 0:e1 1:f1 2:f0
    bvs[t] = (which == 2) ? Wout[t] : w1g[t];
    __syncthreads();
    if (t < 160) {
      const int i = t >> 1, s = t & 1;
      const float* row;
      if (which == 0)
        row = (i < 64) ? Wemb + (size_t)i * DM : (i == 64) ? bemb : nullptr;
      else
        row = (i < 65) ? F0r + (size_t)i * DM : nullptr;
      float a = row ? dot32f4(row + s * 128, bvs + s * 128) : 0.f;
      a += __shfl_down(a, 1);
      if (s == 0) {
        if (which == 0) e1g[i] = a;
        else if (which == 1) f1g[i] = a;
        else f0g[i] = a;
      }
    }
  }
}

// ---------------------------------------------------------------------------
// K_post (4 blocks x 1024): 7-step chain in 80-dim space.
// ---------------------------------------------------------------------------
__global__ __launch_bounds__(1024, 4)
void k_post(const float* __restrict__ Xp, const float* __restrict__ cp,
            const float* __restrict__ C0, const float* __restrict__ C0T,
            const float* __restrict__ C1, const float* __restrict__ CY,
            const float* __restrict__ D1, const float* __restrict__ DY,
            const float* __restrict__ eog, const float* __restrict__ f0g,
            const float* __restrict__ e1g, const float* __restrict__ f1g,
            const float* __restrict__ bout, float* __restrict__ out) {
  const int b = blockIdx.x, t = threadIdx.x;
  __shared__ __align__(16) float X[80][81];
  __shared__ __align__(16) float cl[DP], eo[DP], f0[DP], e1[DP], f1[DP];
  __shared__ __align__(16) float cM0[DP], g8[DP], y8[DP], qv[DP];
  __shared__ __align__(16) float rE[DP], rF[DP], t1v[DP], Xq[DP];
  __shared__ __align__(16) float pr0[DP], pr1[DP], pr2[DP];
  __shared__ float dots[3];

  // ---- P0: X core reduce + cl + small-vector staging + X pads
  {
    const int e = t * 4;
    const float* base = Xp + (size_t)b * NCH * 4096 + e;
    float4 a0 = make_float4(0.f, 0.f, 0.f, 0.f), a1 = a0, a2 = a0, a3 = a0;
#pragma unroll
    for (int ch = 0; ch < NCH; ch += 4) {
      const float4 p0 = *reinterpret_cast<const float4*>(base + (size_t)ch * 4096);
      const float4 p1 = *reinterpret_cast<const float4*>(base + (size_t)(ch + 1) * 4096);
      const float4 p2 = *reinterpret_cast<const float4*>(base + (size_t)(ch + 2) * 4096);
      const float4 p3 = *reinterpret_cast<const float4*>(base + (size_t)(ch + 3) * 4096);
      a0.x += p0.x; a0.y += p0.y; a0.z += p0.z; a0.w += p0.w;
      a1.x += p1.x; a1.y += p1.y; a1.z += p1.z; a1.w += p1.w;
      a2.x += p2.x; a2.y += p2.y; a2.z += p2.z; a2.w += p2.w;
      a3.x += p3.x; a3.y += p3.y; a3.z += p3.z; a3.w += p3.w;
    }
    const float4 s = make_float4((a0.x + a1.x) + (a2.x + a3.x),
                                 (a0.y + a1.y) + (a2.y + a3.y),
                                 (a0.z + a1.z) + (a2.z + a3.z),
                                 (a0.w + a1.w) + (a2.w + a3.w));
    const int r = t >> 4, c = (t & 15) * 4;
    X[r][c] = s.x; X[r][c + 1] = s.y; X[r][c + 2] = s.z; X[r][c + 3] = s.w;

    if (t < 64) {
      const float* cb = cp + (size_t)b * NCH * 64 + t;
      float v0 = 0.f, v1 = 0.f, v2 = 0.f, v3 = 0.f;
#pragma unroll
      for (int ch = 0; ch < NCH; ch += 4) {
        v0 += cb[(size_t)(ch + 0) * 64]; v1 += cb[(size_t)(ch + 1) * 64];
        v2 += cb[(size_t)(ch + 2) * 64]; v3 += cb[(size_t)(ch + 3) * 64];
      }
      cl[t] = (v0 + v1) + (v2 + v3);
    } else if (t == 64) cl[64] = (float)SEQ;
    else if (t < 80) cl[t] = 0.f;
    else if (t >= 128 && t < 208) eo[t - 128] = eog[t - 128];
    else if (t >= 208 && t < 288) f0[t - 208] = f0g[t - 208];
    else if (t >= 288 && t < 368) e1[t - 288] = e1g[t - 288];
    else if (t >= 368 && t < 448) f1[t - 368] = f1g[t - 368];
    if (t >= 448) {
      for (int n = t - 448; n < 2255; n += 576) {
        if (n < 1040) X[n >> 4][65 + (n & 15)] = 0.f;
        else { const int m = n - 1040; X[65 + m / 81][m % 81] = 0.f; }
      }
    }
  }
  __syncthreads();

  // ---- S1: cM0 = C0·cl || X borders || pr0 = cl*eo
  if (t < 320) {
    const int j = t >> 2, s = t & 3;
    float a = dot5f4(C0 + j * DP + s * 20, cl + s * 20);
    a += __shfl_down(a, 2); a += __shfl_down(a, 1);
    if (s == 0) cM0[j] = a;
  } else if (t >= 384 && t < 513) {
    const int n = t - 384;
    if (n < 64) X[n][64] = cl[n];
    else if (n == 64) X[64][64] = (float)SEQ;
    else X[64][n - 65] = cl[n - 65];
  } else if (t >= 576 && t < 656) {
    const int i = t - 576; pr0[i] = cl[i] * eo[i];
  }
  __syncthreads();

  // ---- S2 (LDS): g = cM0·X || y = X·f1
  if (t < 320) {
    const int j = t >> 2, s = t & 3;
    float a = 0.f;
    for (int i = s * 20; i < s * 20 + 20; ++i) a += cM0[i] * X[i][j];
    a += __shfl_down(a, 2); a += __shfl_down(a, 1);
    if (s == 0) g8[j] = a;
  } else if (t < 640) {
    const int u = t - 320, i = u >> 2, s = u & 3;
    float a = 0.f;
    for (int j = s * 20; j < s * 20 + 20; ++j) a += X[i][j] * f1[j];
    a += __shfl_down(a, 2); a += __shfl_down(a, 1);
    if (s == 0) y8[i] = a;
  }
  __syncthreads();

  // ---- S3: rE = C1·cl + a·CY·g || rF = D1·cl + a·DY·g || qv = e1 + a·C0T·y
  if (t < 320) {
    const int j = t >> 2, s = t & 3;
    float a = (s < 2) ? dot10f4(C1 + j * DP + s * 40, cl + s * 40)
                      : ALPHA * dot10f4(CY + j * DP + (s - 2) * 40, g8 + (s - 2) * 40);
    a += __shfl_down(a, 2); a += __shfl_down(a, 1);
    if (s == 0) rE[j] = a;
  } else if (t < 640) {
    const int u = t - 320, j = u >> 2, s = u & 3;
    float a = (s < 2) ? dot10f4(D1 + j * DP + s * 40, cl + s * 40)
                      : ALPHA * dot10f4(DY + j * DP + (s - 2) * 40, g8 + (s - 2) * 40);
    a += __shfl_down(a, 2); a += __shfl_down(a, 1);
    if (s == 0) rF[j] = a;
  } else if (t < 960) {
    const int u = t - 640, j = u >> 2, s = u & 3;
    float a = dot5f4(C0T + j * DP + s * 20, y8 + s * 20);
    a += __shfl_down(a, 2); a += __shfl_down(a, 1);
    if (s == 0) qv[j] = e1[j] + ALPHA * a;
  }
  __syncthreads();

  // ---- S4 (LDS): t1 = rF·X || Xq = X·qv || pr1 = g*f0
  if (t < 320) {
    const int j = t >> 2, s = t & 3;
    float a = 0.f;
    for (int i = s * 20; i < s * 20 + 20; ++i) a += rF[i] * X[i][j];
    a += __shfl_down(a, 2); a += __shfl_down(a, 1);
    if (s == 0) t1v[j] = a;
  } else if (t < 640) {
    const int u = t - 320, i = u >> 2, s = u & 3;
    float a = 0.f;
    for (int j = s * 20; j < s * 20 + 20; ++j) a += X[i][j] * qv[j];
    a += __shfl_down(a, 2); a += __shfl_down(a, 1);
    if (s == 0) Xq[i] = a;
  } else if (t < 720) {
    const int i = t - 640; pr1[i] = g8[i] * f0[i];
  }
  __syncthreads();

  // ---- S5: pr2 = (rE + a·C0T·t1) * Xq
  if (t < 320) {
    const int j = t >> 2, s = t & 3;
    float a = dot5f4(C0T + j * DP + s * 20, t1v + s * 20);
    a += __shfl_down(a, 2); a += __shfl_down(a, 1);
    if (s == 0) pr2[j] = (rE[j] + ALPHA * a) * Xq[j];
  }
  __syncthreads();

  // ---- S6: three 80-dots + out
  const int w = t >> 6, l = t & 63;
  if (w < 3) {
    const float* pr = (w == 0) ? pr0 : (w == 1) ? pr1 : pr2;
    float v = pr[l] + ((l < 16) ? pr[64 + l] : 0.f);
    v = wave_red(v);
    if (l == 0) dots[w] = v;
  }
  __syncthreads();
  if (t == 0) out[b] = dots[0] + ALPHA * dots[1] + ALPHA * dots[2] + bout[0];
}

}  // namespace

extern "C" void kernel_launch(void* const* d_in, const int* in_sizes, int n_in,
                              void* d_out, int out_size, void* d_ws, size_t ws_size,
                              hipStream_t stream) {
  const float* x    = (const float*)d_in[0];
  const float* Wemb = (const float*)d_in[1];
  const float* bemb = (const float*)d_in[2];
  const float* Wq   = (const float*)d_in[3];
  const float* Wk   = (const float*)d_in[4];
  const float* Wv   = (const float*)d_in[5];
  const float* Wout = (const float*)d_in[6];
  const float* bout = (const float*)d_in[7];
  float* out = (float*)d_out;

  float* p = (float*)d_ws;
  float* Xp   = p; p += (size_t)BATCH * NCH * 4096;
  float* cp   = p; p += (size_t)BATCH * NCH * 64;
  float* F0r  = p; p += DP * 256;
  float* P0r  = p; p += DP * 256;
  float* K0r  = p; p += DP * 256;
  float* P1r  = p; p += DP * 256;
  float* K1r  = p; p += DP * 256;
  float* PF1r = p; p += DP * 256;
  float* KF1r = p; p += DP * 256;
  float* w1g  = p; p += 256;
  float* eog  = p; p += 80;
  float* e1g  = p; p += 80;
  float* f1g  = p; p += 80;
  float* f0g  = p; p += 80;
  float* C0   = p; p += DP * DP;
  float* C0T  = p; p += DP * DP;
  float* C1   = p; p += DP * DP;
  float* CY   = p; p += DP * DP;
  float* D1   = p; p += DP * DP;
  float* DY   = p; p += DP * DP;

  k_pre<<<361, 256, 0, stream>>>(x, Wemb, bemb, Wq, Wk, Wv, Wout,
                                 Xp, cp, F0r, P0r, K0r, P1r, K1r, PF1r, KF1r,
                                 w1g, eog);
  k_mid<<<403, 256, 0, stream>>>(Wemb, bemb, Wout, F0r, P0r, K0r, P1r, K1r,
                                 PF1r, KF1r, w1g, C0, C0T, C1, CY, D1, DY,
                                 e1g, f1g, f0g);
  k_post<<<BATCH, 1024, 0, stream>>>(Xp, cp, C0, C0T, C1, CY, D1, DY,
                                     eog, f0g, e1g, f1g, bout, out);
}